// Round 9
// baseline (311.435 us; speedup 1.0000x reference)
//
#include <hip/hip_runtime.h>
#include <hip/hip_bf16.h>
#include <hip/hip_cooperative_groups.h>

namespace cg = cooperative_groups;

#define N_NODES 4096
#define D_MODEL 256
#define NWORDS 128   // bitmap words per row (4096/32)
#define MAXC 512     // max neighbors per row (avg ~33)

typedef __attribute__((ext_vector_type(8))) short short8;
typedef __attribute__((ext_vector_type(4))) float f32x4;

__device__ __forceinline__ unsigned short f2b(float f) {  // fp32 -> bf16 RTN
    unsigned u = __float_as_uint(f);
    return (unsigned short)((u + 0x7FFFu + ((u >> 16) & 1u)) >> 16);
}
__device__ __forceinline__ float b2f(unsigned short u) {
    return __uint_as_float((unsigned)u << 16);
}

struct KArgs {
    const float *x, *Wq, *bq, *Wk, *bk, *Wv, *bv, *Wo, *bo;
    const float *g1, *b1, *g2, *b2, *Wm1, *bm1, *Wm2, *bm2;
    const int* ei;
    int E, nadj;
    int* flag;
    unsigned* bitmap;
    unsigned short *wbf, *h, *qkv, *y, *m1;
    float *x1, *psum, *psum2, *out;
    const unsigned short *WTqkv, *WTo, *WTm1, *WTm2;
};

union SMem {
    struct {
        unsigned short A[64][72];
        unsigned short B[64][72];
        float psA[64][2], psA2[64][2];
        float muS[64], invS[64];
    } g;                                      // ~20 KB (GEMM phases)
    struct { int sIdx[2][MAXC]; int wsum[2][2]; int scnt[2]; } a;  // attn
    struct { float red[8]; } l;               // LN
};

// ---- GEMM tile: 64x64, 512 thr / 8 waves (wave = 16x32, 1x2 frags), BK=64
// MODE 1: +bias,GELU->bf16 | 2: +bias+R->f32 | 3: qkv 3-part bias->bf16
// LNA: A=f32 + precomputed partial stats, LN applied during staging
// STATS: epilogue emits per-row partial sum/sumsq of C
template <int K, int MODE, bool LNA, bool STATS>
__device__ __forceinline__ void d_gemm(int w, const unsigned short* A,
        const float* Af, const float* psum, const float* psum2,
        const float* lng, const float* lnb, const unsigned short* BT,
        const float* bias, const float* bias_k, const float* bias_v,
        const float* R, float* Cf, unsigned short* Cb,
        float* opsum, float* opsum2, int M, SMem& sm) {
    int tid = threadIdx.x;
    int brow = (w & 63) << 6;
    int by   = w >> 6;
    int bcol = by << 6;
    int wid = tid >> 6, lane = tid & 63;
    int wr = wid >> 1, wc = wid & 1;
    int l15 = lane & 15, lhi = lane >> 4;
    int r0 = tid >> 3, c0 = (tid & 7) << 3;

    float mu_r = 0.f, inv_r = 0.f;
    if (LNA) {
        if (tid < 64) {
            float4 s4 = ((const float4*)psum)[brow + tid];
            float4 q4 = ((const float4*)psum2)[brow + tid];
            float S  = s4.x + s4.y + s4.z + s4.w;
            float S2 = q4.x + q4.y + q4.z + q4.w;
            float mu = S * (1.0f / 256.0f);
            sm.g.muS[tid]  = mu;
            sm.g.invS[tid] = rsqrtf(S2 * (1.0f / 256.0f) - mu * mu + 1e-5f);
        }
        __syncthreads();
        mu_r = sm.g.muS[r0]; inv_r = sm.g.invS[r0];
    }

    const unsigned short* Bp = BT + (size_t)(bcol + r0) * K + c0;
    f32x4 acc[2] = {};
    short8 areg;
    float4 xa, xb, ga, gb, ba, bb;
    if (LNA) {
        const float* Xp = Af + (size_t)(brow + r0) * 256 + c0;
        xa = *(const float4*)(Xp);
        xb = *(const float4*)(Xp + 4);
        ga = *(const float4*)(lng + c0); gb = *(const float4*)(lng + c0 + 4);
        ba = *(const float4*)(lnb + c0); bb = *(const float4*)(lnb + c0 + 4);
    } else {
        areg = *(const short8*)(A + (size_t)(brow + r0) * K + c0);
    }
    short8 breg = *(const short8*)(Bp);

    #pragma unroll
    for (int k0 = 0; k0 < K; k0 += 64) {
        if (LNA) {
            float xv[8] = {xa.x, xa.y, xa.z, xa.w, xb.x, xb.y, xb.z, xb.w};
            float gv[8] = {ga.x, ga.y, ga.z, ga.w, gb.x, gb.y, gb.z, gb.w};
            float bv[8] = {ba.x, ba.y, ba.z, ba.w, bb.x, bb.y, bb.z, bb.w};
            short8 o;
            #pragma unroll
            for (int j = 0; j < 8; ++j)
                o[j] = (short)f2b((xv[j] - mu_r) * inv_r * gv[j] + bv[j]);
            *(short8*)&sm.g.A[r0][c0] = o;
        } else {
            *(short8*)&sm.g.A[r0][c0] = areg;
        }
        *(short8*)&sm.g.B[r0][c0] = breg;
        __syncthreads();
        if (k0 + 64 < K) {                     // prefetch next K-step
            if (LNA) {
                const float* Xp = Af + (size_t)(brow + r0) * 256 + k0 + 64 + c0;
                xa = *(const float4*)(Xp);
                xb = *(const float4*)(Xp + 4);
                ga = *(const float4*)(lng + k0 + 64 + c0);
                gb = *(const float4*)(lng + k0 + 64 + c0 + 4);
                ba = *(const float4*)(lnb + k0 + 64 + c0);
                bb = *(const float4*)(lnb + k0 + 64 + c0 + 4);
            } else {
                areg = *(const short8*)(A + (size_t)(brow + r0) * K + k0 + 64 + c0);
            }
            breg = *(const short8*)(Bp + k0 + 64);
        }
        #pragma unroll
        for (int ks = 0; ks < 2; ++ks) {
            int kc = ks * 32 + lhi * 8;
            short8 a_0 = *(const short8*)&sm.g.A[wr * 16 + l15][kc];
            short8 b_0 = *(const short8*)&sm.g.B[wc * 32 + l15][kc];
            short8 b_1 = *(const short8*)&sm.g.B[wc * 32 + 16 + l15][kc];
            acc[0] = __builtin_amdgcn_mfma_f32_16x16x32_bf16(a_0, b_0, acc[0], 0, 0, 0);
            acc[1] = __builtin_amdgcn_mfma_f32_16x16x32_bf16(a_0, b_1, acc[1], 0, 0, 0);
        }
        __syncthreads();
    }

    float cs[2][4];
    #pragma unroll
    for (int sn = 0; sn < 2; ++sn) {
        int col = bcol + wc * 32 + sn * 16 + l15;
        float bs;
        if (MODE == 3)
            bs = (col < 256) ? bias[col]
               : (col < 512) ? bias_k[col - 256] : bias_v[col - 512];
        else
            bs = bias[col];
        #pragma unroll
        for (int r = 0; r < 4; ++r) {
            int row = brow + wr * 16 + lhi * 4 + r;
            float c = acc[sn][r] + bs;
            if (MODE == 1) {
                c = 0.5f * c * (1.0f + erff(c * 0.70710678118654752f));
                Cb[(size_t)row * M + col] = f2b(c);
            } else if (MODE == 2) {
                c += R[(size_t)row * M + col];
                Cf[(size_t)row * M + col] = c;
            } else {
                Cb[(size_t)row * M + col] = f2b(c);
            }
            if (STATS) cs[sn][r] = c;
        }
    }
    if (STATS) {
        #pragma unroll
        for (int r = 0; r < 4; ++r) {
            float s  = cs[0][r] + cs[1][r];
            float s2 = cs[0][r] * cs[0][r] + cs[1][r] * cs[1][r];
            #pragma unroll
            for (int off = 1; off < 16; off <<= 1) {
                s  += __shfl_xor(s, off, 64);
                s2 += __shfl_xor(s2, off, 64);
            }
            if (l15 == 0) {
                int rl = wr * 16 + lhi * 4 + r;
                sm.g.psA[rl][wc] = s; sm.g.psA2[rl][wc] = s2;
            }
        }
        __syncthreads();
        if (tid < 64) {
            opsum [(size_t)(brow + tid) * 4 + by] = sm.g.psA[tid][0] + sm.g.psA[tid][1];
            opsum2[(size_t)(brow + tid) * 4 + by] = sm.g.psA2[tid][0] + sm.g.psA2[tid][1];
        }
        __syncthreads();
    }
}

// ---- Phase 0: convw | zero bitmap | detect | LN1 -------------------------
__device__ __forceinline__ void phase0(const KArgs& a, SMem& sm, int bid, int G) {
    int t = threadIdx.x;
    for (int w = bid; w < 1024; w += G) {          // weights -> bf16 [M][K]
        int e = w * 512 + t;
        const float* W; int base, K, M;
        if (e < 262144) {
            int r = e >> 16;
            W = (r == 0) ? a.Wq : (r == 1) ? a.Wk : (r == 2) ? a.Wv : a.Wo;
            base = r << 16; K = 256; M = 256;
        } else if (e < 393216) { W = a.Wm1; base = 262144; K = 256; M = 512; }
        else                   { W = a.Wm2; base = 393216; K = 512; M = 256; }
        int i = e - base;
        int m = i / K, k = i - m * K;
        a.wbf[e] = f2b(W[(size_t)k * M + m]);
    }
    for (int w = bid; w < 256; w += G)             // zero 2MB bitmap
        ((uint4*)a.bitmap)[(size_t)w * 512 + t] = uint4{0, 0, 0, 0};
    if (bid == 0 && t == 0) {                      // edge dtype detect
        int is64 = 1;
        for (int i = 1; i < 128; i += 2)
            if (a.ei[i] != 0) { is64 = 0; break; }
        *a.flag = is64;
    }
    for (int w = bid; w < 2048; w += G) {          // LN1: 2 rows per block
        int row = (w << 1) + (t >> 8), col = t & 255;
        float v = a.x[(size_t)row * 256 + col];
        float s = v;
        #pragma unroll
        for (int off = 32; off; off >>= 1) s += __shfl_down(s, off, 64);
        if ((t & 63) == 0) sm.l.red[t >> 6] = s;
        __syncthreads();
        int rb = (t >> 8) << 2;
        float mu = (sm.l.red[rb] + sm.l.red[rb + 1] + sm.l.red[rb + 2] +
                    sm.l.red[rb + 3]) * (1.0f / 256.0f);
        __syncthreads();
        float d = v - mu, s2 = d * d;
        #pragma unroll
        for (int off = 32; off; off >>= 1) s2 += __shfl_down(s2, off, 64);
        if ((t & 63) == 0) sm.l.red[t >> 6] = s2;
        __syncthreads();
        float var = (sm.l.red[rb] + sm.l.red[rb + 1] + sm.l.red[rb + 2] +
                     sm.l.red[rb + 3]) * (1.0f / 256.0f);
        a.h[(size_t)row * 256 + col] =
            f2b(d * rsqrtf(var + 1e-5f) * a.g1[col] + a.b1[col]);
        __syncthreads();
    }
}

// ---- Phase 1: adj scatter + qkv GEMM -------------------------------------
__device__ __forceinline__ void phase1(const KArgs& a, SMem& sm, int bid, int G) {
    int t = threadIdx.x;
    int f64 = *(volatile int*)a.flag;
    for (int w = bid; w < a.nadj; w += G) {
        int e = w * 512 + t;
        if (e < a.E) {
            int n, m;
            if (f64) { n = a.ei[2 * e]; m = a.ei[2 * (a.E + e)]; }
            else     { n = a.ei[e];     m = a.ei[a.E + e]; }
            atomicOr(&a.bitmap[n * NWORDS + (m >> 5)], 1u << (m & 31));
        }
    }
    for (int w = bid; w < 768; w += G)
        d_gemm<256, 3, false, false>(w, a.h, nullptr, nullptr, nullptr, nullptr,
            nullptr, a.WTqkv, a.bq, a.bk, a.bv, nullptr, nullptr, a.qkv,
            nullptr, nullptr, 768, sm);
}

// ---- Phase 2: sparse attention, 2 rows per block -------------------------
__device__ __forceinline__ void phase2(const KArgs& a, SMem& sm, int bid, int G) {
    int t = threadIdx.x;
    for (int w = bid; w < 2048; w += G) {
        int g = t >> 8, lt = t & 255;
        int n = (w << 1) + g;
        int hh = lt >> 5, lane = lt & 31;
        const unsigned short* qp = a.qkv + (size_t)n * 768 + hh * 32;
        float qreg[32];
        #pragma unroll
        for (int i = 0; i < 4; ++i) {
            short8 q8 = *(const short8*)(qp + i * 8);
            #pragma unroll
            for (int j = 0; j < 8; ++j) qreg[i * 8 + j] = b2f((unsigned short)q8[j]);
        }
        unsigned word = 0; int pc = 0, pre = 0;
        if (lt < 128) {
            word = a.bitmap[n * NWORDS + lt];
            pc = __popc(word); pre = pc;
            #pragma unroll
            for (int off = 1; off < 64; off <<= 1) {
                int u = __shfl_up(pre, off, 64);
                if ((t & 63) >= off) pre += u;
            }
            if ((t & 63) == 63) sm.a.wsum[g][lt >> 6] = pre;
        }
        __syncthreads();
        if (lt < 128) {
            int base = (lt >= 64) ? sm.a.wsum[g][0] : 0;
            int off = base + pre - pc;
            while (word) {
                int bit = __ffs(word) - 1;
                word &= word - 1;
                if (off < MAXC) sm.a.sIdx[g][off] = (lt << 5) + bit;
                ++off;
            }
            if (lt == 127) sm.a.scnt[g] = min(base + pre, MAXC);
        }
        __syncthreads();
        int c = sm.a.scnt[g];
        const float scl = 0.17677669529663687f;   // 1/sqrt(32)
        float m_run = -INFINITY, S = 0.0f, acc = 0.0f;
        for (int b0 = 0; b0 < c; b0 += 32) {
            int j = b0 + lane;
            float s = -INFINITY;
            if (j < c) {
                const unsigned short* kp =
                    a.qkv + (size_t)sm.a.sIdx[g][j] * 768 + 256 + hh * 32;
                float d = 0.0f;
                #pragma unroll
                for (int i = 0; i < 4; ++i) {
                    short8 k8 = *(const short8*)(kp + i * 8);
                    #pragma unroll
                    for (int e = 0; e < 8; ++e)
                        d = fmaf(qreg[i * 8 + e], b2f((unsigned short)k8[e]), d);
                }
                s = d * scl;
            }
            float bm = s;
            #pragma unroll
            for (int off = 16; off; off >>= 1) bm = fmaxf(bm, __shfl_xor(bm, off, 32));
            float newM = fmaxf(m_run, bm);
            float p = (j < c) ? __expf(s - newM) : 0.0f;
            float bs = p;
            #pragma unroll
            for (int off = 16; off; off >>= 1) bs += __shfl_xor(bs, off, 32);
            float scale = __expf(m_run - newM);
            S = S * scale + bs;
            acc *= scale;
            int lim = min(32, c - b0);
            const unsigned short* vbase = a.qkv + 512 + hh * 32 + lane;
            #pragma unroll 4
            for (int jj = 0; jj < lim; ++jj) {
                float pj = __shfl(p, jj, 32);
                int m = sm.a.sIdx[g][b0 + jj];
                acc = fmaf(pj, b2f(vbase[(size_t)m * 768]), acc);
            }
            m_run = newM;
        }
        a.y[(size_t)n * 256 + hh * 32 + lane] = f2b(acc / S);
        __syncthreads();
    }
}

__device__ __forceinline__ void phase3(const KArgs& a, SMem& sm, int bid, int G) {
    for (int w = bid; w < 256; w += G)
        d_gemm<256, 2, false, true>(w, a.y, nullptr, nullptr, nullptr, nullptr,
            nullptr, a.WTo, a.bo, nullptr, nullptr, a.x, a.x1, nullptr,
            a.psum, a.psum2, 256, sm);
}
__device__ __forceinline__ void phase4(const KArgs& a, SMem& sm, int bid, int G) {
    for (int w = bid; w < 512; w += G)
        d_gemm<256, 1, true, false>(w, nullptr, a.x1, a.psum, a.psum2, a.g2,
            a.b2, a.WTm1, a.bm1, nullptr, nullptr, nullptr, nullptr, a.m1,
            nullptr, nullptr, 512, sm);
}
__device__ __forceinline__ void phase5(const KArgs& a, SMem& sm, int bid, int G) {
    for (int w = bid; w < 256; w += G)
        d_gemm<512, 2, false, false>(w, a.m1, nullptr, nullptr, nullptr, nullptr,
            nullptr, a.WTm2, a.bm2, nullptr, nullptr, a.x1, a.out, nullptr,
            nullptr, nullptr, 256, sm);
}

// ---- cooperative mega-kernel: all phases, grid.sync between --------------
__global__ __launch_bounds__(512, 4) void mega_kernel(KArgs a) {
    __shared__ SMem sm;
    cg::grid_group grid = cg::this_grid();
    int bid = blockIdx.x, G = gridDim.x;
    phase0(a, sm, bid, G);  grid.sync();
    phase1(a, sm, bid, G);  grid.sync();
    phase2(a, sm, bid, G);  grid.sync();
    phase3(a, sm, bid, G);  grid.sync();
    phase4(a, sm, bid, G);  grid.sync();
    phase5(a, sm, bid, G);
}

// ---- fallback: same phases as 6 plain kernels ----------------------------
__global__ __launch_bounds__(512, 4) void k_p0(KArgs a) { __shared__ SMem sm; phase0(a, sm, blockIdx.x, gridDim.x); }
__global__ __launch_bounds__(512, 4) void k_p1(KArgs a) { __shared__ SMem sm; phase1(a, sm, blockIdx.x, gridDim.x); }
__global__ __launch_bounds__(512, 4) void k_p2(KArgs a) { __shared__ SMem sm; phase2(a, sm, blockIdx.x, gridDim.x); }
__global__ __launch_bounds__(512, 4) void k_p3(KArgs a) { __shared__ SMem sm; phase3(a, sm, blockIdx.x, gridDim.x); }
__global__ __launch_bounds__(512, 4) void k_p4(KArgs a) { __shared__ SMem sm; phase4(a, sm, blockIdx.x, gridDim.x); }
__global__ __launch_bounds__(512, 4) void k_p5(KArgs a) { __shared__ SMem sm; phase5(a, sm, blockIdx.x, gridDim.x); }

extern "C" void kernel_launch(void* const* d_in, const int* in_sizes, int n_in,
                              void* d_out, int out_size, void* d_ws, size_t ws_size,
                              hipStream_t stream) {
    KArgs a;
    a.x   = (const float*)d_in[0];
    a.ei  = (const int*)d_in[1];
    a.Wq  = (const float*)d_in[2];  a.bq  = (const float*)d_in[3];
    a.Wk  = (const float*)d_in[4];  a.bk  = (const float*)d_in[5];
    a.Wv  = (const float*)d_in[6];  a.bv  = (const float*)d_in[7];
    a.Wo  = (const float*)d_in[8];  a.bo  = (const float*)d_in[9];
    a.g1  = (const float*)d_in[10]; a.b1  = (const float*)d_in[11];
    a.g2  = (const float*)d_in[12]; a.b2  = (const float*)d_in[13];
    a.Wm1 = (const float*)d_in[14]; a.bm1 = (const float*)d_in[15];
    a.Wm2 = (const float*)d_in[16]; a.bm2 = (const float*)d_in[17];
    a.out = (float*)d_out;
    a.E = in_sizes[1] / 2;                  // 135168
    a.nadj = (a.E + 511) / 512;

    char* WS = (char*)d_ws;
    const size_t MB = 1u << 20;
    a.bitmap = (unsigned*)WS;                               // [0,2MB)
    a.flag   = (int*)(WS + 2 * MB);                         // 4B
    a.psum   = (float*)(WS + 2 * MB + 4096);                // 64KB [N][4]
    a.psum2  = (float*)(WS + 2 * MB + 4096 + 65536);        // 64KB
    a.wbf    = (unsigned short*)(WS + 3 * MB);              // 1MB
    a.y      = (unsigned short*)(WS + 4 * MB);              // 2MB
    a.x1     = (float*)(WS + 6 * MB);                       // 4MB
    a.m1     = (unsigned short*)(WS + 10 * MB);             // 4MB
    a.h      = (unsigned short*)(WS + 14 * MB);             // 2MB
    a.qkv    = (unsigned short*)(WS + 16 * MB);             // 6MB

    a.WTqkv = a.wbf;                        // q|k|v stacked along M
    a.WTo   = a.wbf + 196608;
    a.WTm1  = a.wbf + 262144;
    a.WTm2  = a.wbf + 393216;

    int occ = 0;
    hipError_t oe = hipOccupancyMaxActiveBlocksPerMultiprocessor(&occ, mega_kernel, 512, 0);
    bool coop = (oe == hipSuccess && occ > 0);
    if (coop) {
        int G = occ * 256; if (G > 1024) G = 1024;
        void* kp[] = { (void*)&a };
        hipError_t le = hipLaunchCooperativeKernel(mega_kernel, dim3(G), dim3(512),
                                                   kp, 0, stream);
        if (le != hipSuccess) coop = false;
    }
    if (!coop) {   // fallback: identical phases, 6 plain launches
        k_p0<<<2048, 512, 0, stream>>>(a);
        k_p1<<<1032, 512, 0, stream>>>(a);
        k_p2<<<2048, 512, 0, stream>>>(a);
        k_p3<<<256,  512, 0, stream>>>(a);
        k_p4<<<512,  512, 0, stream>>>(a);
        k_p5<<<256,  512, 0, stream>>>(a);
    }
}

// Round 10
// 305.477 us; speedup vs baseline: 1.0195x; 1.0195x over previous
//
#include <hip/hip_runtime.h>
#include <hip/hip_bf16.h>
#include <hip/hip_cooperative_groups.h>

namespace cg = cooperative_groups;

#define N_NODES 4096
#define D_MODEL 256
#define NWORDS 128   // bitmap words per row (4096/32)
#define MAXC 512     // max neighbors per row (avg ~33)

typedef __attribute__((ext_vector_type(8))) short short8;
typedef __attribute__((ext_vector_type(4))) float f32x4;

__device__ __forceinline__ unsigned short f2b(float f) {  // fp32 -> bf16 RTN
    unsigned u = __float_as_uint(f);
    return (unsigned short)((u + 0x7FFFu + ((u >> 16) & 1u)) >> 16);
}
__device__ __forceinline__ float b2f(unsigned short u) {
    return __uint_as_float((unsigned)u << 16);
}

struct KArgs {
    const float *x, *Wq, *bq, *Wk, *bk, *Wv, *bv, *Wo, *bo;
    const float *g1, *b1, *g2, *b2, *Wm1, *bm1, *Wm2, *bm2;
    const int* ei;
    int E, nadj;
    int* flag;
    unsigned* bitmap;
    unsigned short *wbf, *h, *qkv, *y, *m1;
    float *x1, *psum, *psum2, *out;
    const unsigned short *WTqkv, *WTo, *WTm1, *WTm2;
};

union SMem {
    struct {
        unsigned short A[64][72];
        unsigned short B[64][72];
        float psA[64][2], psA2[64][2];
        float muS[64], invS[64];
    } g;                                      // ~20 KB (GEMM phases)
    struct { int sIdx[2][MAXC]; int wsum[2][2]; int scnt[2]; } a;  // attn
    struct { float red[8]; } l;               // LN
};

// ---- GEMM tile: 64x64, 512 thr / 8 waves (wave = 16x32, 1x2 frags), BK=64
// MODE 1: +bias,GELU->bf16 | 2: +bias+R->f32 | 3: qkv 3-part bias->bf16
// LNA: A=f32 + precomputed partial stats, LN applied during staging
// STATS: epilogue emits per-row partial sum/sumsq of C
template <int K, int MODE, bool LNA, bool STATS>
__device__ __forceinline__ void d_gemm(int w, const unsigned short* A,
        const float* Af, const float* psum, const float* psum2,
        const float* lng, const float* lnb, const unsigned short* BT,
        const float* bias, const float* bias_k, const float* bias_v,
        const float* R, float* Cf, unsigned short* Cb,
        float* opsum, float* opsum2, int M, SMem& sm) {
    int tid = threadIdx.x;
    int brow = (w & 63) << 6;
    int by   = w >> 6;
    int bcol = by << 6;
    int wid = tid >> 6, lane = tid & 63;
    int wr = wid >> 1, wc = wid & 1;
    int l15 = lane & 15, lhi = lane >> 4;
    int r0 = tid >> 3, c0 = (tid & 7) << 3;

    float mu_r = 0.f, inv_r = 0.f;
    if (LNA) {
        if (tid < 64) {
            float4 s4 = ((const float4*)psum)[brow + tid];
            float4 q4 = ((const float4*)psum2)[brow + tid];
            float S  = s4.x + s4.y + s4.z + s4.w;
            float S2 = q4.x + q4.y + q4.z + q4.w;
            float mu = S * (1.0f / 256.0f);
            sm.g.muS[tid]  = mu;
            sm.g.invS[tid] = rsqrtf(S2 * (1.0f / 256.0f) - mu * mu + 1e-5f);
        }
        __syncthreads();
        mu_r = sm.g.muS[r0]; inv_r = sm.g.invS[r0];
    }

    const unsigned short* Bp = BT + (size_t)(bcol + r0) * K + c0;
    f32x4 acc[2] = {};
    short8 areg;
    float4 xa, xb, ga, gb, ba, bb;
    if (LNA) {
        const float* Xp = Af + (size_t)(brow + r0) * 256 + c0;
        xa = *(const float4*)(Xp);
        xb = *(const float4*)(Xp + 4);
        ga = *(const float4*)(lng + c0); gb = *(const float4*)(lng + c0 + 4);
        ba = *(const float4*)(lnb + c0); bb = *(const float4*)(lnb + c0 + 4);
    } else {
        areg = *(const short8*)(A + (size_t)(brow + r0) * K + c0);
    }
    short8 breg = *(const short8*)(Bp);

    #pragma unroll
    for (int k0 = 0; k0 < K; k0 += 64) {
        if (LNA) {
            float xv[8] = {xa.x, xa.y, xa.z, xa.w, xb.x, xb.y, xb.z, xb.w};
            float gv[8] = {ga.x, ga.y, ga.z, ga.w, gb.x, gb.y, gb.z, gb.w};
            float bv[8] = {ba.x, ba.y, ba.z, ba.w, bb.x, bb.y, bb.z, bb.w};
            short8 o;
            #pragma unroll
            for (int j = 0; j < 8; ++j)
                o[j] = (short)f2b((xv[j] - mu_r) * inv_r * gv[j] + bv[j]);
            *(short8*)&sm.g.A[r0][c0] = o;
        } else {
            *(short8*)&sm.g.A[r0][c0] = areg;
        }
        *(short8*)&sm.g.B[r0][c0] = breg;
        __syncthreads();
        if (k0 + 64 < K) {                     // prefetch next K-step
            if (LNA) {
                const float* Xp = Af + (size_t)(brow + r0) * 256 + k0 + 64 + c0;
                xa = *(const float4*)(Xp);
                xb = *(const float4*)(Xp + 4);
                ga = *(const float4*)(lng + k0 + 64 + c0);
                gb = *(const float4*)(lng + k0 + 64 + c0 + 4);
                ba = *(const float4*)(lnb + k0 + 64 + c0);
                bb = *(const float4*)(lnb + k0 + 64 + c0 + 4);
            } else {
                areg = *(const short8*)(A + (size_t)(brow + r0) * K + k0 + 64 + c0);
            }
            breg = *(const short8*)(Bp + k0 + 64);
        }
        #pragma unroll
        for (int ks = 0; ks < 2; ++ks) {
            int kc = ks * 32 + lhi * 8;
            short8 a_0 = *(const short8*)&sm.g.A[wr * 16 + l15][kc];
            short8 b_0 = *(const short8*)&sm.g.B[wc * 32 + l15][kc];
            short8 b_1 = *(const short8*)&sm.g.B[wc * 32 + 16 + l15][kc];
            acc[0] = __builtin_amdgcn_mfma_f32_16x16x32_bf16(a_0, b_0, acc[0], 0, 0, 0);
            acc[1] = __builtin_amdgcn_mfma_f32_16x16x32_bf16(a_0, b_1, acc[1], 0, 0, 0);
        }
        __syncthreads();
    }

    float cs[2][4];
    #pragma unroll
    for (int sn = 0; sn < 2; ++sn) {
        int col = bcol + wc * 32 + sn * 16 + l15;
        float bs;
        if (MODE == 3)
            bs = (col < 256) ? bias[col]
               : (col < 512) ? bias_k[col - 256] : bias_v[col - 512];
        else
            bs = bias[col];
        #pragma unroll
        for (int r = 0; r < 4; ++r) {
            int row = brow + wr * 16 + lhi * 4 + r;
            float c = acc[sn][r] + bs;
            if (MODE == 1) {
                c = 0.5f * c * (1.0f + erff(c * 0.70710678118654752f));
                Cb[(size_t)row * M + col] = f2b(c);
            } else if (MODE == 2) {
                c += R[(size_t)row * M + col];
                Cf[(size_t)row * M + col] = c;
            } else {
                Cb[(size_t)row * M + col] = f2b(c);
            }
            if (STATS) cs[sn][r] = c;
        }
    }
    if (STATS) {
        #pragma unroll
        for (int r = 0; r < 4; ++r) {
            float s  = cs[0][r] + cs[1][r];
            float s2 = cs[0][r] * cs[0][r] + cs[1][r] * cs[1][r];
            #pragma unroll
            for (int off = 1; off < 16; off <<= 1) {
                s  += __shfl_xor(s, off, 64);
                s2 += __shfl_xor(s2, off, 64);
            }
            if (l15 == 0) {
                int rl = wr * 16 + lhi * 4 + r;
                sm.g.psA[rl][wc] = s; sm.g.psA2[rl][wc] = s2;
            }
        }
        __syncthreads();
        if (tid < 64) {
            opsum [(size_t)(brow + tid) * 4 + by] = sm.g.psA[tid][0] + sm.g.psA[tid][1];
            opsum2[(size_t)(brow + tid) * 4 + by] = sm.g.psA2[tid][0] + sm.g.psA2[tid][1];
        }
        __syncthreads();
    }
}

// ---- Phase 0: convw | zero bitmap | detect | LN1 -------------------------
__device__ __forceinline__ void phase0(const KArgs& a, SMem& sm, int bid, int G) {
    int t = threadIdx.x;
    for (int w = bid; w < 1024; w += G) {          // weights -> bf16 [M][K]
        int e = w * 512 + t;
        const float* W; int base, K, M;
        if (e < 262144) {
            int r = e >> 16;
            W = (r == 0) ? a.Wq : (r == 1) ? a.Wk : (r == 2) ? a.Wv : a.Wo;
            base = r << 16; K = 256; M = 256;
        } else if (e < 393216) { W = a.Wm1; base = 262144; K = 256; M = 512; }
        else                   { W = a.Wm2; base = 393216; K = 512; M = 256; }
        int i = e - base;
        int m = i / K, k = i - m * K;
        a.wbf[e] = f2b(W[(size_t)k * M + m]);
    }
    for (int w = bid; w < 256; w += G)             // zero 2MB bitmap
        ((uint4*)a.bitmap)[(size_t)w * 512 + t] = uint4{0, 0, 0, 0};
    if (bid == 0 && t == 0) {                      // edge dtype detect
        int is64 = 1;
        for (int i = 1; i < 128; i += 2)
            if (a.ei[i] != 0) { is64 = 0; break; }
        *a.flag = is64;
    }
    for (int w = bid; w < 2048; w += G) {          // LN1: 2 rows per block
        int row = (w << 1) + (t >> 8), col = t & 255;
        float v = a.x[(size_t)row * 256 + col];
        float s = v;
        #pragma unroll
        for (int off = 32; off; off >>= 1) s += __shfl_down(s, off, 64);
        if ((t & 63) == 0) sm.l.red[t >> 6] = s;
        __syncthreads();
        int rb = (t >> 8) << 2;
        float mu = (sm.l.red[rb] + sm.l.red[rb + 1] + sm.l.red[rb + 2] +
                    sm.l.red[rb + 3]) * (1.0f / 256.0f);
        __syncthreads();
        float d = v - mu, s2 = d * d;
        #pragma unroll
        for (int off = 32; off; off >>= 1) s2 += __shfl_down(s2, off, 64);
        if ((t & 63) == 0) sm.l.red[t >> 6] = s2;
        __syncthreads();
        float var = (sm.l.red[rb] + sm.l.red[rb + 1] + sm.l.red[rb + 2] +
                     sm.l.red[rb + 3]) * (1.0f / 256.0f);
        a.h[(size_t)row * 256 + col] =
            f2b(d * rsqrtf(var + 1e-5f) * a.g1[col] + a.b1[col]);
        __syncthreads();
    }
}

// ---- Phase 1: adj scatter + qkv GEMM -------------------------------------
__device__ __forceinline__ void phase1(const KArgs& a, SMem& sm, int bid, int G) {
    int t = threadIdx.x;
    int f64 = *(volatile int*)a.flag;
    for (int w = bid; w < a.nadj; w += G) {
        int e = w * 512 + t;
        if (e < a.E) {
            int n, m;
            if (f64) { n = a.ei[2 * e]; m = a.ei[2 * (a.E + e)]; }
            else     { n = a.ei[e];     m = a.ei[a.E + e]; }
            atomicOr(&a.bitmap[n * NWORDS + (m >> 5)], 1u << (m & 31));
        }
    }
    for (int w = bid; w < 768; w += G)
        d_gemm<256, 3, false, false>(w, a.h, nullptr, nullptr, nullptr, nullptr,
            nullptr, a.WTqkv, a.bq, a.bk, a.bv, nullptr, nullptr, a.qkv,
            nullptr, nullptr, 768, sm);
}

// ---- Phase 2: sparse attention, 2 rows per block -------------------------
__device__ __forceinline__ void phase2(const KArgs& a, SMem& sm, int bid, int G) {
    int t = threadIdx.x;
    for (int w = bid; w < 2048; w += G) {
        int g = t >> 8, lt = t & 255;
        int n = (w << 1) + g;
        int hh = lt >> 5, lane = lt & 31;
        const unsigned short* qp = a.qkv + (size_t)n * 768 + hh * 32;
        float qreg[32];
        #pragma unroll
        for (int i = 0; i < 4; ++i) {
            short8 q8 = *(const short8*)(qp + i * 8);
            #pragma unroll
            for (int j = 0; j < 8; ++j) qreg[i * 8 + j] = b2f((unsigned short)q8[j]);
        }
        unsigned word = 0; int pc = 0, pre = 0;
        if (lt < 128) {
            word = a.bitmap[n * NWORDS + lt];
            pc = __popc(word); pre = pc;
            #pragma unroll
            for (int off = 1; off < 64; off <<= 1) {
                int u = __shfl_up(pre, off, 64);
                if ((t & 63) >= off) pre += u;
            }
            if ((t & 63) == 63) sm.a.wsum[g][lt >> 6] = pre;
        }
        __syncthreads();
        if (lt < 128) {
            int base = (lt >= 64) ? sm.a.wsum[g][0] : 0;
            int off = base + pre - pc;
            while (word) {
                int bit = __ffs(word) - 1;
                word &= word - 1;
                if (off < MAXC) sm.a.sIdx[g][off] = (lt << 5) + bit;
                ++off;
            }
            if (lt == 127) sm.a.scnt[g] = min(base + pre, MAXC);
        }
        __syncthreads();
        int c = sm.a.scnt[g];
        const float scl = 0.17677669529663687f;   // 1/sqrt(32)
        float m_run = -INFINITY, S = 0.0f, acc = 0.0f;
        for (int b0 = 0; b0 < c; b0 += 32) {
            int j = b0 + lane;
            float s = -INFINITY;
            if (j < c) {
                const unsigned short* kp =
                    a.qkv + (size_t)sm.a.sIdx[g][j] * 768 + 256 + hh * 32;
                float d = 0.0f;
                #pragma unroll
                for (int i = 0; i < 4; ++i) {
                    short8 k8 = *(const short8*)(kp + i * 8);
                    #pragma unroll
                    for (int e = 0; e < 8; ++e)
                        d = fmaf(qreg[i * 8 + e], b2f((unsigned short)k8[e]), d);
                }
                s = d * scl;
            }
            float bm = s;
            #pragma unroll
            for (int off = 16; off; off >>= 1) bm = fmaxf(bm, __shfl_xor(bm, off, 32));
            float newM = fmaxf(m_run, bm);
            float p = (j < c) ? __expf(s - newM) : 0.0f;
            float bs = p;
            #pragma unroll
            for (int off = 16; off; off >>= 1) bs += __shfl_xor(bs, off, 32);
            float scale = __expf(m_run - newM);
            S = S * scale + bs;
            acc *= scale;
            int lim = min(32, c - b0);
            const unsigned short* vbase = a.qkv + 512 + hh * 32 + lane;
            #pragma unroll 4
            for (int jj = 0; jj < lim; ++jj) {
                float pj = __shfl(p, jj, 32);
                int m = sm.a.sIdx[g][b0 + jj];
                acc = fmaf(pj, b2f(vbase[(size_t)m * 768]), acc);
            }
            m_run = newM;
        }
        a.y[(size_t)n * 256 + hh * 32 + lane] = f2b(acc / S);
        __syncthreads();
    }
}

__device__ __forceinline__ void phase3(const KArgs& a, SMem& sm, int bid, int G) {
    for (int w = bid; w < 256; w += G)
        d_gemm<256, 2, false, true>(w, a.y, nullptr, nullptr, nullptr, nullptr,
            nullptr, a.WTo, a.bo, nullptr, nullptr, a.x, a.x1, nullptr,
            a.psum, a.psum2, 256, sm);
}
__device__ __forceinline__ void phase4(const KArgs& a, SMem& sm, int bid, int G) {
    for (int w = bid; w < 512; w += G)
        d_gemm<256, 1, true, false>(w, nullptr, a.x1, a.psum, a.psum2, a.g2,
            a.b2, a.WTm1, a.bm1, nullptr, nullptr, nullptr, nullptr, a.m1,
            nullptr, nullptr, 512, sm);
}
__device__ __forceinline__ void phase5(const KArgs& a, SMem& sm, int bid, int G) {
    for (int w = bid; w < 256; w += G)
        d_gemm<512, 2, false, false>(w, a.m1, nullptr, nullptr, nullptr, nullptr,
            nullptr, a.WTm2, a.bm2, nullptr, nullptr, a.x1, a.out, nullptr,
            nullptr, nullptr, 256, sm);
}

// ---- cooperative mega-kernel: all phases, grid.sync between --------------
// NOTE: no min-occupancy clamp — round-9's (512,4) capped VGPRs at 60 and
// spilled qreg/staging to scratch (42MB scratch writes, 5x slowdown).
__global__ __launch_bounds__(512) void mega_kernel(KArgs a) {
    __shared__ SMem sm;
    cg::grid_group grid = cg::this_grid();
    int bid = blockIdx.x, G = gridDim.x;
    phase0(a, sm, bid, G);  grid.sync();
    phase1(a, sm, bid, G);  grid.sync();
    phase2(a, sm, bid, G);  grid.sync();
    phase3(a, sm, bid, G);  grid.sync();
    phase4(a, sm, bid, G);  grid.sync();
    phase5(a, sm, bid, G);
}

// ---- fallback: same phases as 6 plain kernels ----------------------------
__global__ __launch_bounds__(512) void k_p0(KArgs a) { __shared__ SMem sm; phase0(a, sm, blockIdx.x, gridDim.x); }
__global__ __launch_bounds__(512) void k_p1(KArgs a) { __shared__ SMem sm; phase1(a, sm, blockIdx.x, gridDim.x); }
__global__ __launch_bounds__(512) void k_p2(KArgs a) { __shared__ SMem sm; phase2(a, sm, blockIdx.x, gridDim.x); }
__global__ __launch_bounds__(512) void k_p3(KArgs a) { __shared__ SMem sm; phase3(a, sm, blockIdx.x, gridDim.x); }
__global__ __launch_bounds__(512) void k_p4(KArgs a) { __shared__ SMem sm; phase4(a, sm, blockIdx.x, gridDim.x); }
__global__ __launch_bounds__(512) void k_p5(KArgs a) { __shared__ SMem sm; phase5(a, sm, blockIdx.x, gridDim.x); }

extern "C" void kernel_launch(void* const* d_in, const int* in_sizes, int n_in,
                              void* d_out, int out_size, void* d_ws, size_t ws_size,
                              hipStream_t stream) {
    KArgs a;
    a.x   = (const float*)d_in[0];
    a.ei  = (const int*)d_in[1];
    a.Wq  = (const float*)d_in[2];  a.bq  = (const float*)d_in[3];
    a.Wk  = (const float*)d_in[4];  a.bk  = (const float*)d_in[5];
    a.Wv  = (const float*)d_in[6];  a.bv  = (const float*)d_in[7];
    a.Wo  = (const float*)d_in[8];  a.bo  = (const float*)d_in[9];
    a.g1  = (const float*)d_in[10]; a.b1  = (const float*)d_in[11];
    a.g2  = (const float*)d_in[12]; a.b2  = (const float*)d_in[13];
    a.Wm1 = (const float*)d_in[14]; a.bm1 = (const float*)d_in[15];
    a.Wm2 = (const float*)d_in[16]; a.bm2 = (const float*)d_in[17];
    a.out = (float*)d_out;
    a.E = in_sizes[1] / 2;                  // 135168
    a.nadj = (a.E + 511) / 512;

    char* WS = (char*)d_ws;
    const size_t MB = 1u << 20;
    a.bitmap = (unsigned*)WS;                               // [0,2MB)
    a.flag   = (int*)(WS + 2 * MB);                         // 4B
    a.psum   = (float*)(WS + 2 * MB + 4096);                // 64KB [N][4]
    a.psum2  = (float*)(WS + 2 * MB + 4096 + 65536);        // 64KB
    a.wbf    = (unsigned short*)(WS + 3 * MB);              // 1MB
    a.y      = (unsigned short*)(WS + 4 * MB);              // 2MB
    a.x1     = (float*)(WS + 6 * MB);                       // 4MB
    a.m1     = (unsigned short*)(WS + 10 * MB);             // 4MB
    a.h      = (unsigned short*)(WS + 14 * MB);             // 2MB
    a.qkv    = (unsigned short*)(WS + 16 * MB);             // 6MB

    a.WTqkv = a.wbf;                        // q|k|v stacked along M
    a.WTo   = a.wbf + 196608;
    a.WTm1  = a.wbf + 262144;
    a.WTm2  = a.wbf + 393216;

    int occ = 0;
    hipError_t oe = hipOccupancyMaxActiveBlocksPerMultiprocessor(&occ, mega_kernel, 512, 0);
    bool coop = (oe == hipSuccess && occ > 0);
    if (coop) {
        int G = occ * 256; if (G > 2048) G = 2048;
        void* kp[] = { (void*)&a };
        hipError_t le = hipLaunchCooperativeKernel(mega_kernel, dim3(G), dim3(512),
                                                   kp, 0, stream);
        if (le != hipSuccess) coop = false;
    }
    if (!coop) {   // fallback: identical phases, 6 plain launches
        k_p0<<<2048, 512, 0, stream>>>(a);
        k_p1<<<1032, 512, 0, stream>>>(a);
        k_p2<<<2048, 512, 0, stream>>>(a);
        k_p3<<<256,  512, 0, stream>>>(a);
        k_p4<<<512,  512, 0, stream>>>(a);
        k_p5<<<256,  512, 0, stream>>>(a);
    }
}

// Round 11
// 105.787 us; speedup vs baseline: 2.9440x; 2.8877x over previous
//
#include <hip/hip_runtime.h>
#include <hip/hip_bf16.h>

#define N_NODES 4096
#define D_MODEL 256
#define NWORDS 128   // bitmap words per row (4096/32)
#define MAXC 512     // max neighbors per row (avg ~33)

typedef __attribute__((ext_vector_type(8))) short short8;
typedef __attribute__((ext_vector_type(4))) float f32x4;

__device__ __forceinline__ unsigned short f2b(float f) {  // fp32 -> bf16 RTN
    unsigned u = __float_as_uint(f);
    return (unsigned short)((u + 0x7FFFu + ((u >> 16) & 1u)) >> 16);
}
__device__ __forceinline__ float b2f(unsigned short u) {
    return __uint_as_float((unsigned)u << 16);
}

// ---- prep: convw (0..2047) | zero bitmap (2048..2559) | detect (2560)
// ----       | LN1 rows (2561..6656) ---------------------------------------
__global__ __launch_bounds__(256) void prep_kernel(const float* __restrict__ Wq,
        const float* __restrict__ Wk, const float* __restrict__ Wv,
        const float* __restrict__ Wo, const float* __restrict__ Wm1,
        const float* __restrict__ Wm2, unsigned short* __restrict__ wbf,
        uint4* __restrict__ bitmap, const int* __restrict__ ei,
        int* __restrict__ flag, const float* __restrict__ x,
        const float* __restrict__ g1, const float* __restrict__ b1,
        unsigned short* __restrict__ h) {
    int b = blockIdx.x, t = threadIdx.x;
    if (b < 2048) {                       // weight fp32 [K][M] -> bf16 [M][K]
        int e = b * 256 + t;              // 0..524287
        const float* W; int base, K, M;
        if (e < 262144) {
            int r = e >> 16;
            W = (r == 0) ? Wq : (r == 1) ? Wk : (r == 2) ? Wv : Wo;
            base = r << 16; K = 256; M = 256;
        } else if (e < 393216) { W = Wm1; base = 262144; K = 256; M = 512; }
        else                   { W = Wm2; base = 393216; K = 512; M = 256; }
        int i = e - base;
        int m = i / K, k = i - m * K;
        wbf[e] = f2b(W[k * M + m]);
    } else if (b < 2560) {                // zero the 2MB bitmap
        bitmap[(size_t)(b - 2048) * 256 + t] = uint4{0, 0, 0, 0};
    } else if (b == 2560) {               // edge dtype detect
        if (t == 0) {
            int is64 = 1;
            for (int i = 1; i < 128; i += 2)
                if (ei[i] != 0) { is64 = 0; break; }
            *flag = is64;
        }
    } else {                              // LayerNorm1: one row per block
        int row = b - 2561;
        float v = x[row * D_MODEL + t];
        __shared__ float red[4];
        float s = v;
        #pragma unroll
        for (int off = 32; off; off >>= 1) s += __shfl_down(s, off, 64);
        if ((t & 63) == 0) red[t >> 6] = s;
        __syncthreads();
        float mu = (red[0] + red[1] + red[2] + red[3]) * (1.0f / 256.0f);
        __syncthreads();
        float d = v - mu;
        float s2 = d * d;
        #pragma unroll
        for (int off = 32; off; off >>= 1) s2 += __shfl_down(s2, off, 64);
        if ((t & 63) == 0) red[t >> 6] = s2;
        __syncthreads();
        float var = (red[0] + red[1] + red[2] + red[3]) * (1.0f / 256.0f);
        h[row * D_MODEL + t] = f2b(d * rsqrtf(var + 1e-5f) * g1[t] + b1[t]);
    }
}

// ---- bf16 MFMA GEMM: 64x64 tile, 512 thr / 8 waves, BK=64 ----------------
// MODE 1: +bias,GELU -> bf16 | 2: +bias+R -> f32 | 3: qkv 3-part bias -> bf16
//   (MODE 3 additionally runs build_adj in blocks [0,nadj) )
// LNA:   A is f32 + per-row partial stats -> layernorm during A-staging
// STATS: epilogue emits per-row partial sum/sumsq of C (for downstream LN)
template <int K, int MODE, bool LNA, bool STATS>
__global__ __launch_bounds__(512) void gemm_bf16(const unsigned short* __restrict__ A,
        const float* __restrict__ Af, const float* __restrict__ psum,
        const float* __restrict__ psum2, const float* __restrict__ lng,
        const float* __restrict__ lnb, const unsigned short* __restrict__ BT,
        const float* __restrict__ bias, const float* __restrict__ bias_k,
        const float* __restrict__ bias_v, const float* __restrict__ R,
        float* __restrict__ Cf, unsigned short* __restrict__ Cb,
        float* __restrict__ opsum, float* __restrict__ opsum2, int M,
        const int* __restrict__ ei, int E, const int* __restrict__ flag,
        unsigned* __restrict__ bitmap, int nadj) {
    int tid = threadIdx.x;
    if (MODE == 3 && (int)blockIdx.x < nadj) {   // fused edge scatter
        int e = (int)blockIdx.x * 512 + tid;
        if (e < E) {
            int n, m;
            if (*flag) { n = ei[2 * e]; m = ei[2 * (E + e)]; }
            else       { n = ei[e];     m = ei[E + e]; }
            atomicOr(&bitmap[n * NWORDS + (m >> 5)], 1u << (m & 31));
        }
        return;
    }
    __shared__ unsigned short Asm[64][72];
    __shared__ unsigned short Bsm[64][72];
    __shared__ float psA[64][2], psA2[64][2];
    __shared__ float muS[64], invS[64];

    int bx2  = (MODE == 3) ? ((int)blockIdx.x - nadj) : 0;
    int brow = (MODE == 3) ? ((bx2 & 63) << 6) : ((int)blockIdx.x << 6);
    int by   = (MODE == 3) ? (bx2 >> 6) : (int)blockIdx.y;
    int bcol = by << 6;
    int wid = tid >> 6, lane = tid & 63;
    int wr = wid >> 1, wc = wid & 1;             // 4 row-waves x 2 col-waves
    int l15 = lane & 15, lhi = lane >> 4;
    int r0 = tid >> 3, c0 = (tid & 7) << 3;

    float mu_r = 0.f, inv_r = 0.f;
    if (LNA) {   // combine partial stats once per block
        if (tid < 64) {
            float4 s4 = ((const float4*)psum)[brow + tid];
            float4 q4 = ((const float4*)psum2)[brow + tid];
            float S  = s4.x + s4.y + s4.z + s4.w;
            float S2 = q4.x + q4.y + q4.z + q4.w;
            float mu = S * (1.0f / 256.0f);
            muS[tid] = mu;
            invS[tid] = rsqrtf(S2 * (1.0f / 256.0f) - mu * mu + 1e-5f);
        }
        __syncthreads();
        mu_r = muS[r0]; inv_r = invS[r0];
    }

    const unsigned short* Bp = BT + (size_t)(bcol + r0) * K + c0;
    f32x4 acc[2] = {};
    short8 areg;
    float4 xa, xb, ga, gb, ba, bb;
    if (LNA) {
        const float* Xp = Af + (size_t)(brow + r0) * 256 + c0;
        xa = *(const float4*)(Xp);
        xb = *(const float4*)(Xp + 4);
        ga = *(const float4*)(lng + c0); gb = *(const float4*)(lng + c0 + 4);
        ba = *(const float4*)(lnb + c0); bb = *(const float4*)(lnb + c0 + 4);
    } else {
        areg = *(const short8*)(A + (size_t)(brow + r0) * K + c0);
    }
    short8 breg = *(const short8*)(Bp);

    #pragma unroll
    for (int k0 = 0; k0 < K; k0 += 64) {
        if (LNA) {   // layernorm on the fly into LDS
            float xv[8] = {xa.x, xa.y, xa.z, xa.w, xb.x, xb.y, xb.z, xb.w};
            float gv[8] = {ga.x, ga.y, ga.z, ga.w, gb.x, gb.y, gb.z, gb.w};
            float bv[8] = {ba.x, ba.y, ba.z, ba.w, bb.x, bb.y, bb.z, bb.w};
            short8 o;
            #pragma unroll
            for (int j = 0; j < 8; ++j)
                o[j] = (short)f2b((xv[j] - mu_r) * inv_r * gv[j] + bv[j]);
            *(short8*)&Asm[r0][c0] = o;
        } else {
            *(short8*)&Asm[r0][c0] = areg;
        }
        *(short8*)&Bsm[r0][c0] = breg;
        __syncthreads();
        if (k0 + 64 < K) {                      // prefetch next K-step
            if (LNA) {
                const float* Xp = Af + (size_t)(brow + r0) * 256 + k0 + 64 + c0;
                xa = *(const float4*)(Xp);
                xb = *(const float4*)(Xp + 4);
                ga = *(const float4*)(lng + k0 + 64 + c0);
                gb = *(const float4*)(lng + k0 + 64 + c0 + 4);
                ba = *(const float4*)(lnb + k0 + 64 + c0);
                bb = *(const float4*)(lnb + k0 + 64 + c0 + 4);
            } else {
                areg = *(const short8*)(A + (size_t)(brow + r0) * K + k0 + 64 + c0);
            }
            breg = *(const short8*)(Bp + k0 + 64);
        }
        #pragma unroll
        for (int ks = 0; ks < 2; ++ks) {
            int kc = ks * 32 + lhi * 8;
            short8 a_0 = *(const short8*)&Asm[wr * 16 + l15][kc];
            short8 b_0 = *(const short8*)&Bsm[wc * 32 + l15][kc];
            short8 b_1 = *(const short8*)&Bsm[wc * 32 + 16 + l15][kc];
            acc[0] = __builtin_amdgcn_mfma_f32_16x16x32_bf16(a_0, b_0, acc[0], 0, 0, 0);
            acc[1] = __builtin_amdgcn_mfma_f32_16x16x32_bf16(a_0, b_1, acc[1], 0, 0, 0);
        }
        __syncthreads();
    }

    float cs[2][4];
    #pragma unroll
    for (int sn = 0; sn < 2; ++sn) {
        int col = bcol + wc * 32 + sn * 16 + l15;
        float bs;
        if (MODE == 3)
            bs = (col < 256) ? bias[col]
               : (col < 512) ? bias_k[col - 256] : bias_v[col - 512];
        else
            bs = bias[col];
        #pragma unroll
        for (int r = 0; r < 4; ++r) {
            int row = brow + wr * 16 + lhi * 4 + r;
            float c = acc[sn][r] + bs;
            if (MODE == 1) {
                c = 0.5f * c * (1.0f + erff(c * 0.70710678118654752f));
                Cb[(size_t)row * M + col] = f2b(c);
            } else if (MODE == 2) {
                c += R[(size_t)row * M + col];
                Cf[(size_t)row * M + col] = c;
            } else {
                Cb[(size_t)row * M + col] = f2b(c);
            }
            if (STATS) cs[sn][r] = c;
        }
    }
    if (STATS) {   // deterministic per-row partial stats over this 64-col strip
        #pragma unroll
        for (int r = 0; r < 4; ++r) {
            float s  = cs[0][r] + cs[1][r];
            float s2 = cs[0][r] * cs[0][r] + cs[1][r] * cs[1][r];
            #pragma unroll
            for (int off = 1; off < 16; off <<= 1) {
                s  += __shfl_xor(s, off, 64);
                s2 += __shfl_xor(s2, off, 64);
            }
            if (l15 == 0) {
                int rl = wr * 16 + lhi * 4 + r;
                psA[rl][wc] = s; psA2[rl][wc] = s2;
            }
        }
        __syncthreads();
        if (tid < 64) {
            opsum [(size_t)(brow + tid) * 4 + by] = psA[tid][0] + psA[tid][1];
            opsum2[(size_t)(brow + tid) * 4 + by] = psA2[tid][0] + psA2[tid][1];
        }
    }
}

// ---------------- sparse attention, pipelined ------------------------------
// qkv: [N][768] bf16 (q|k|v). 1 block/row, 8 head-groups of 32 lanes.
// New vs round 8: sIdx padded to x32 (fixed-32 fully-unrolled PV so all 32
// V-gathers issue together), K-tile register prefetch across batches, and
// 4-way partial FMA chains for ILP.
__global__ __launch_bounds__(256) void attn_kernel(const unsigned short* __restrict__ qkv,
        const unsigned* __restrict__ bitmap, unsigned short* __restrict__ y) {
    int n = blockIdx.x, tid = threadIdx.x;
    int h = tid >> 5, lane = tid & 31;
    __shared__ int sIdx[MAXC];
    __shared__ int wsum[2];
    __shared__ int scnt;

    // q load first: global latency hides under the bitmap scan
    const unsigned short* qp = qkv + (size_t)n * 768 + h * 32;
    float qreg[32];
    #pragma unroll
    for (int i = 0; i < 4; ++i) {
        short8 q8 = *(const short8*)(qp + i * 8);
        #pragma unroll
        for (int j = 0; j < 8; ++j) qreg[i * 8 + j] = b2f((unsigned short)q8[j]);
    }

    unsigned word = 0; int pc = 0, pre = 0;
    if (tid < 128) {                       // popc prefix scan of 128 words
        word = bitmap[n * NWORDS + tid];
        pc = __popc(word);
        pre = pc;
        #pragma unroll
        for (int off = 1; off < 64; off <<= 1) {
            int u = __shfl_up(pre, off, 64);
            if ((tid & 63) >= off) pre += u;
        }
        if ((tid & 63) == 63) wsum[tid >> 6] = pre;
    }
    __syncthreads();
    if (tid < 128) {
        int base = (tid >= 64) ? wsum[0] : 0;
        int off = base + pre - pc;
        while (word) {
            int bit = __ffs(word) - 1;
            word &= word - 1;
            if (off < MAXC) sIdx[off] = (tid << 5) + bit;
            ++off;
        }
        if (tid == 127) scnt = min(base + pre, MAXC);
    }
    __syncthreads();
    int c = scnt;
    int cpad = (c + 31) & ~31;
    for (int i = c + tid; i < cpad; i += 256) sIdx[i] = 0;   // pad: safe index
    __syncthreads();

    const float sc = 0.17677669529663687f;   // 1/sqrt(32)
    float m_run = -INFINITY, S = 0.0f, acc = 0.0f;

    // preload K tile for batch 0 (padded-safe indices)
    const unsigned short* kp = qkv + (size_t)sIdx[lane] * 768 + 256 + h * 32;
    short8 k0 = *(const short8*)(kp);
    short8 k1 = *(const short8*)(kp + 8);
    short8 k2 = *(const short8*)(kp + 16);
    short8 k3 = *(const short8*)(kp + 24);

    for (int b0 = 0; b0 < c; b0 += 32) {
        // prefetch next batch's K while this batch computes
        short8 n0 = {}, n1 = {}, n2 = {}, n3 = {};
        bool more = (b0 + 32) < c;          // uniform per block (c uniform)
        if (more) {
            const unsigned short* kpn =
                qkv + (size_t)sIdx[b0 + 32 + lane] * 768 + 256 + h * 32;
            n0 = *(const short8*)(kpn);
            n1 = *(const short8*)(kpn + 8);
            n2 = *(const short8*)(kpn + 16);
            n3 = *(const short8*)(kpn + 24);
        }
        int j = b0 + lane;
        float d0 = 0.f, d1 = 0.f, d2 = 0.f, d3 = 0.f;
        #pragma unroll
        for (int e = 0; e < 8; ++e) {
            d0 = fmaf(qreg[e],      b2f((unsigned short)k0[e]), d0);
            d1 = fmaf(qreg[8 + e],  b2f((unsigned short)k1[e]), d1);
            d2 = fmaf(qreg[16 + e], b2f((unsigned short)k2[e]), d2);
            d3 = fmaf(qreg[24 + e], b2f((unsigned short)k3[e]), d3);
        }
        float s = (j < c) ? ((d0 + d1) + (d2 + d3)) * sc : -INFINITY;
        float bm = s;
        #pragma unroll
        for (int off = 16; off; off >>= 1) bm = fmaxf(bm, __shfl_xor(bm, off, 32));
        float newM = fmaxf(m_run, bm);
        float p = (j < c) ? __expf(s - newM) : 0.0f;
        float bs = p;
        #pragma unroll
        for (int off = 16; off; off >>= 1) bs += __shfl_xor(bs, off, 32);
        float scale = __expf(m_run - newM);
        S = S * scale + bs;
        acc *= scale;
        const unsigned short* vbase = qkv + 512 + h * 32 + lane;
        float a0 = 0.f, a1 = 0.f, a2 = 0.f, a3 = 0.f;
        #pragma unroll
        for (int jj = 0; jj < 32; jj += 4) {   // fixed 32: p=0 kills padding
            float p0 = __shfl(p, jj,     32);
            float p1 = __shfl(p, jj + 1, 32);
            float p2 = __shfl(p, jj + 2, 32);
            float p3 = __shfl(p, jj + 3, 32);
            a0 = fmaf(p0, b2f(vbase[(size_t)sIdx[b0 + jj    ] * 768]), a0);
            a1 = fmaf(p1, b2f(vbase[(size_t)sIdx[b0 + jj + 1] * 768]), a1);
            a2 = fmaf(p2, b2f(vbase[(size_t)sIdx[b0 + jj + 2] * 768]), a2);
            a3 = fmaf(p3, b2f(vbase[(size_t)sIdx[b0 + jj + 3] * 768]), a3);
        }
        acc += (a0 + a1) + (a2 + a3);
        m_run = newM;
        k0 = n0; k1 = n1; k2 = n2; k3 = n3;
    }
    y[(size_t)n * 256 + h * 32 + lane] = f2b(acc / S);
}

extern "C" void kernel_launch(void* const* d_in, const int* in_sizes, int n_in,
                              void* d_out, int out_size, void* d_ws, size_t ws_size,
                              hipStream_t stream) {
    const float* x   = (const float*)d_in[0];
    const int*   ei  = (const int*)d_in[1];
    const float* Wq  = (const float*)d_in[2];  const float* bq  = (const float*)d_in[3];
    const float* Wk  = (const float*)d_in[4];  const float* bk  = (const float*)d_in[5];
    const float* Wv  = (const float*)d_in[6];  const float* bv  = (const float*)d_in[7];
    const float* Wo  = (const float*)d_in[8];  const float* bo  = (const float*)d_in[9];
    const float* g1  = (const float*)d_in[10]; const float* b1  = (const float*)d_in[11];
    const float* g2  = (const float*)d_in[12]; const float* b2  = (const float*)d_in[13];
    const float* Wm1 = (const float*)d_in[14]; const float* bm1 = (const float*)d_in[15];
    const float* Wm2 = (const float*)d_in[16]; const float* bm2 = (const float*)d_in[17];
    float* out = (float*)d_out;
    int E = in_sizes[1] / 2;   // 135168
    int nadj = (E + 511) / 512;

    char* WS = (char*)d_ws;
    const size_t MB = 1u << 20;
    unsigned*       bitmap = (unsigned*)WS;                        // [0,2MB)
    int*            flag   = (int*)(WS + 2 * MB);                  // 4B
    float*          psum   = (float*)(WS + 2 * MB + 4096);         // 64KB [N][4]
    float*          psum2  = (float*)(WS + 2 * MB + 4096 + 65536); // 64KB
    unsigned short* wbf    = (unsigned short*)(WS + 3 * MB);       // 1MB
    unsigned short* y      = (unsigned short*)(WS + 4 * MB);       // 2MB
    float*          x1     = (float*)(WS + 6 * MB);                // 4MB
    unsigned short* m1     = (unsigned short*)(WS + 10 * MB);      // 4MB
    unsigned short* h      = (unsigned short*)(WS + 14 * MB);      // 2MB
    unsigned short* qkv    = (unsigned short*)(WS + 16 * MB);      // 6MB

    const unsigned short* WTqkv = wbf;            // q|k|v stacked along M
    const unsigned short* WTo   = wbf + 196608;
    const unsigned short* WTm1  = wbf + 262144;
    const unsigned short* WTm2  = wbf + 393216;

    // 1) convw + zero bitmap + detect + LN1
    prep_kernel<<<6657, 256, 0, stream>>>(Wq, Wk, Wv, Wo, Wm1, Wm2, wbf,
                                          (uint4*)bitmap, ei, flag, x, g1, b1, h);
    // 2) build_adj (blocks [0,nadj)) + qkv = h @ Wqkv + b (blocks [nadj, nadj+768))
    gemm_bf16<256, 3, false, false><<<nadj + 768, 512, 0, stream>>>(h, nullptr,
            nullptr, nullptr, nullptr, nullptr, WTqkv, bq, bk, bv, nullptr,
            nullptr, qkv, nullptr, nullptr, 768, ei, E, flag, bitmap, nadj);
    // 3) attention
    attn_kernel<<<N_NODES, 256, 0, stream>>>(qkv, bitmap, y);
    // 4) x1 = x + y @ Wo + bo   (+ per-row partial LN2 stats)
    gemm_bf16<256, 2, false, true><<<dim3(64, 4), 512, 0, stream>>>(y, nullptr,
            nullptr, nullptr, nullptr, nullptr, WTo, bo, nullptr, nullptr, x,
            x1, nullptr, psum, psum2, 256, nullptr, 0, nullptr, nullptr, 0);
    // 5) m1 = gelu(LN2(x1) @ Wm1 + bm1)   (LN2 applied during A-staging)
    gemm_bf16<256, 1, true, false><<<dim3(64, 8), 512, 0, stream>>>(nullptr, x1,
            psum, psum2, g2, b2, WTm1, bm1, nullptr, nullptr, nullptr,
            nullptr, m1, nullptr, nullptr, 512, nullptr, 0, nullptr, nullptr, 0);
    // 6) out = x1 + m1 @ Wm2 + bm2
    gemm_bf16<512, 2, false, false><<<dim3(64, 4), 512, 0, stream>>>(m1, nullptr,
            nullptr, nullptr, nullptr, nullptr, WTm2, bm2, nullptr, nullptr, x1,
            out, nullptr, nullptr, nullptr, 256, nullptr, 0, nullptr, nullptr, 0);
}

// Round 12
// 86.212 us; speedup vs baseline: 3.6124x; 1.2270x over previous
//
#include <hip/hip_runtime.h>
#include <hip/hip_bf16.h>

#define N_NODES 4096
#define D_MODEL 256
#define NWORDS 128   // bitmap words per row (4096/32)
#define MAXC 512     // max neighbors per row (avg ~33)

typedef __attribute__((ext_vector_type(8))) short short8;
typedef __attribute__((ext_vector_type(4))) float f32x4;

__device__ __forceinline__ unsigned short f2b(float f) {  // fp32 -> bf16 RTN
    unsigned u = __float_as_uint(f);
    return (unsigned short)((u + 0x7FFFu + ((u >> 16) & 1u)) >> 16);
}
__device__ __forceinline__ float b2f(unsigned short u) {
    return __uint_as_float((unsigned)u << 16);
}

// ---- prep: convw (0..2047) | zero bitmap (2048..2559) | detect (2560)
// ----       | LN1 rows (2561..6656) ---------------------------------------
__global__ __launch_bounds__(256) void prep_kernel(const float* __restrict__ Wq,
        const float* __restrict__ Wk, const float* __restrict__ Wv,
        const float* __restrict__ Wo, const float* __restrict__ Wm1,
        const float* __restrict__ Wm2, unsigned short* __restrict__ wbf,
        uint4* __restrict__ bitmap, const int* __restrict__ ei,
        int* __restrict__ flag, const float* __restrict__ x,
        const float* __restrict__ g1, const float* __restrict__ b1,
        unsigned short* __restrict__ h) {
    int b = blockIdx.x, t = threadIdx.x;
    if (b < 2048) {                       // weight fp32 [K][M] -> bf16 [M][K]
        int e = b * 256 + t;              // 0..524287
        const float* W; int base, K, M;
        if (e < 262144) {
            int r = e >> 16;
            W = (r == 0) ? Wq : (r == 1) ? Wk : (r == 2) ? Wv : Wo;
            base = r << 16; K = 256; M = 256;
        } else if (e < 393216) { W = Wm1; base = 262144; K = 256; M = 512; }
        else                   { W = Wm2; base = 393216; K = 512; M = 256; }
        int i = e - base;
        int m = i / K, k = i - m * K;
        wbf[e] = f2b(W[k * M + m]);
    } else if (b < 2560) {                // zero the 2MB bitmap
        bitmap[(size_t)(b - 2048) * 256 + t] = uint4{0, 0, 0, 0};
    } else if (b == 2560) {               // edge dtype detect
        if (t == 0) {
            int is64 = 1;
            for (int i = 1; i < 128; i += 2)
                if (ei[i] != 0) { is64 = 0; break; }
            *flag = is64;
        }
    } else {                              // LayerNorm1: one row per block
        int row = b - 2561;
        float v = x[row * D_MODEL + t];
        __shared__ float red[4];
        float s = v;
        #pragma unroll
        for (int off = 32; off; off >>= 1) s += __shfl_down(s, off, 64);
        if ((t & 63) == 0) red[t >> 6] = s;
        __syncthreads();
        float mu = (red[0] + red[1] + red[2] + red[3]) * (1.0f / 256.0f);
        __syncthreads();
        float d = v - mu;
        float s2 = d * d;
        #pragma unroll
        for (int off = 32; off; off >>= 1) s2 += __shfl_down(s2, off, 64);
        if ((t & 63) == 0) red[t >> 6] = s2;
        __syncthreads();
        float var = (red[0] + red[1] + red[2] + red[3]) * (1.0f / 256.0f);
        h[row * D_MODEL + t] = f2b(d * rsqrtf(var + 1e-5f) * g1[t] + b1[t]);
    }
}

// ---- bf16 MFMA GEMM: 64x64 tile, 512 thr / 8 waves, BK=64 ----------------
// MODE 1: +bias,GELU -> bf16 | 2: +bias+R -> f32 | 3: qkv 3-part bias,
//   head-major stores q/k/v[h][N][32] (+ build_adj in blocks [0,nadj))
// LNA:   A is f32 + per-row partial stats -> layernorm during A-staging
// STATS: epilogue emits per-row partial sum/sumsq of C (for downstream LN)
template <int K, int MODE, bool LNA, bool STATS>
__global__ __launch_bounds__(512) void gemm_bf16(const unsigned short* __restrict__ A,
        const float* __restrict__ Af, const float* __restrict__ psum,
        const float* __restrict__ psum2, const float* __restrict__ lng,
        const float* __restrict__ lnb, const unsigned short* __restrict__ BT,
        const float* __restrict__ bias, const float* __restrict__ bias_k,
        const float* __restrict__ bias_v, const float* __restrict__ R,
        float* __restrict__ Cf, unsigned short* __restrict__ Cb,
        unsigned short* __restrict__ Ck, unsigned short* __restrict__ Cv,
        float* __restrict__ opsum, float* __restrict__ opsum2, int M,
        const int* __restrict__ ei, int E, const int* __restrict__ flag,
        unsigned* __restrict__ bitmap, int nadj) {
    int tid = threadIdx.x;
    if (MODE == 3 && (int)blockIdx.x < nadj) {   // fused edge scatter
        int e = (int)blockIdx.x * 512 + tid;
        if (e < E) {
            int n, m;
            if (*flag) { n = ei[2 * e]; m = ei[2 * (E + e)]; }
            else       { n = ei[e];     m = ei[E + e]; }
            atomicOr(&bitmap[n * NWORDS + (m >> 5)], 1u << (m & 31));
        }
        return;
    }
    __shared__ unsigned short Asm[64][72];
    __shared__ unsigned short Bsm[64][72];
    __shared__ float psA[64][2], psA2[64][2];
    __shared__ float muS[64], invS[64];

    int bx2  = (MODE == 3) ? ((int)blockIdx.x - nadj) : 0;
    int brow = (MODE == 3) ? ((bx2 & 63) << 6) : ((int)blockIdx.x << 6);
    int by   = (MODE == 3) ? (bx2 >> 6) : (int)blockIdx.y;
    int bcol = by << 6;
    int wid = tid >> 6, lane = tid & 63;
    int wr = wid >> 1, wc = wid & 1;             // 4 row-waves x 2 col-waves
    int l15 = lane & 15, lhi = lane >> 4;
    int r0 = tid >> 3, c0 = (tid & 7) << 3;

    float mu_r = 0.f, inv_r = 0.f;
    if (LNA) {   // combine partial stats once per block
        if (tid < 64) {
            float4 s4 = ((const float4*)psum)[brow + tid];
            float4 q4 = ((const float4*)psum2)[brow + tid];
            float S  = s4.x + s4.y + s4.z + s4.w;
            float S2 = q4.x + q4.y + q4.z + q4.w;
            float mu = S * (1.0f / 256.0f);
            muS[tid] = mu;
            invS[tid] = rsqrtf(S2 * (1.0f / 256.0f) - mu * mu + 1e-5f);
        }
        __syncthreads();
        mu_r = muS[r0]; inv_r = invS[r0];
    }

    const unsigned short* Bp = BT + (size_t)(bcol + r0) * K + c0;
    f32x4 acc[2] = {};
    short8 areg;
    float4 xa, xb, ga, gb, ba, bb;
    if (LNA) {
        const float* Xp = Af + (size_t)(brow + r0) * 256 + c0;
        xa = *(const float4*)(Xp);
        xb = *(const float4*)(Xp + 4);
        ga = *(const float4*)(lng + c0); gb = *(const float4*)(lng + c0 + 4);
        ba = *(const float4*)(lnb + c0); bb = *(const float4*)(lnb + c0 + 4);
    } else {
        areg = *(const short8*)(A + (size_t)(brow + r0) * K + c0);
    }
    short8 breg = *(const short8*)(Bp);

    #pragma unroll
    for (int k0 = 0; k0 < K; k0 += 64) {
        if (LNA) {   // layernorm on the fly into LDS
            float xv[8] = {xa.x, xa.y, xa.z, xa.w, xb.x, xb.y, xb.z, xb.w};
            float gv[8] = {ga.x, ga.y, ga.z, ga.w, gb.x, gb.y, gb.z, gb.w};
            float bv[8] = {ba.x, ba.y, ba.z, ba.w, bb.x, bb.y, bb.z, bb.w};
            short8 o;
            #pragma unroll
            for (int j = 0; j < 8; ++j)
                o[j] = (short)f2b((xv[j] - mu_r) * inv_r * gv[j] + bv[j]);
            *(short8*)&Asm[r0][c0] = o;
        } else {
            *(short8*)&Asm[r0][c0] = areg;
        }
        *(short8*)&Bsm[r0][c0] = breg;
        __syncthreads();
        if (k0 + 64 < K) {                      // prefetch next K-step
            if (LNA) {
                const float* Xp = Af + (size_t)(brow + r0) * 256 + k0 + 64 + c0;
                xa = *(const float4*)(Xp);
                xb = *(const float4*)(Xp + 4);
                ga = *(const float4*)(lng + k0 + 64 + c0);
                gb = *(const float4*)(lng + k0 + 64 + c0 + 4);
                ba = *(const float4*)(lnb + k0 + 64 + c0);
                bb = *(const float4*)(lnb + k0 + 64 + c0 + 4);
            } else {
                areg = *(const short8*)(A + (size_t)(brow + r0) * K + k0 + 64 + c0);
            }
            breg = *(const short8*)(Bp + k0 + 64);
        }
        #pragma unroll
        for (int ks = 0; ks < 2; ++ks) {
            int kc = ks * 32 + lhi * 8;
            short8 a_0 = *(const short8*)&Asm[wr * 16 + l15][kc];
            short8 b_0 = *(const short8*)&Bsm[wc * 32 + l15][kc];
            short8 b_1 = *(const short8*)&Bsm[wc * 32 + 16 + l15][kc];
            acc[0] = __builtin_amdgcn_mfma_f32_16x16x32_bf16(a_0, b_0, acc[0], 0, 0, 0);
            acc[1] = __builtin_amdgcn_mfma_f32_16x16x32_bf16(a_0, b_1, acc[1], 0, 0, 0);
        }
        __syncthreads();
    }

    float cs[2][4];
    #pragma unroll
    for (int sn = 0; sn < 2; ++sn) {
        int col = bcol + wc * 32 + sn * 16 + l15;
        float bs;
        if (MODE == 3)
            bs = (col < 256) ? bias[col]
               : (col < 512) ? bias_k[col - 256] : bias_v[col - 512];
        else
            bs = bias[col];
        #pragma unroll
        for (int r = 0; r < 4; ++r) {
            int row = brow + wr * 16 + lhi * 4 + r;
            float c = acc[sn][r] + bs;
            if (MODE == 1) {
                c = 0.5f * c * (1.0f + erff(c * 0.70710678118654752f));
                Cb[(size_t)row * M + col] = f2b(c);
            } else if (MODE == 2) {
                c += R[(size_t)row * M + col];
                Cf[(size_t)row * M + col] = c;
            } else if (MODE == 3) {
                // head-major: part (q/k/v), head = cc>>5, dim = cc&31
                int part = col >> 8, cc = col & 255;
                unsigned short* dst = (part == 0) ? Cb : (part == 1) ? Ck : Cv;
                dst[(((size_t)(cc >> 5) * N_NODES + row) << 5) + (cc & 31)] = f2b(c);
            } else {
                Cb[(size_t)row * M + col] = f2b(c);
            }
            if (STATS) cs[sn][r] = c;
        }
    }
    if (STATS) {   // deterministic per-row partial stats over this 64-col strip
        #pragma unroll
        for (int r = 0; r < 4; ++r) {
            float s  = cs[0][r] + cs[1][r];
            float s2 = cs[0][r] * cs[0][r] + cs[1][r] * cs[1][r];
            #pragma unroll
            for (int off = 1; off < 16; off <<= 1) {
                s  += __shfl_xor(s, off, 64);
                s2 += __shfl_xor(s2, off, 64);
            }
            if (l15 == 0) {
                int rl = wr * 16 + lhi * 4 + r;
                psA[rl][wc] = s; psA2[rl][wc] = s2;
            }
        }
        __syncthreads();
        if (tid < 64) {
            opsum [(size_t)(brow + tid) * 4 + by] = psA[tid][0] + psA[tid][1];
            opsum2[(size_t)(brow + tid) * 4 + by] = psA2[tid][0] + psA2[tid][1];
        }
    }
}

// ---------------- sparse attention (round-8 structure, head-major q/k/v) --
// q/k/v: [8][N][32] bf16 — each head's gather region is a dense 256KB array.
__global__ __launch_bounds__(256) void attn_kernel(const unsigned short* __restrict__ qh,
        const unsigned short* __restrict__ kh, const unsigned short* __restrict__ vh,
        const unsigned* __restrict__ bitmap, unsigned short* __restrict__ y) {
    int n = blockIdx.x, tid = threadIdx.x;
    int h = tid >> 5, lane = tid & 31;
    __shared__ int sIdx[MAXC];
    __shared__ int wsum[2];
    __shared__ int scnt;

    // q load first: global latency hides under the bitmap scan
    const unsigned short* qp = qh + (((size_t)h * N_NODES + n) << 5);
    float qreg[32];
    #pragma unroll
    for (int i = 0; i < 4; ++i) {
        short8 q8 = *(const short8*)(qp + i * 8);
        #pragma unroll
        for (int j = 0; j < 8; ++j) qreg[i * 8 + j] = b2f((unsigned short)q8[j]);
    }

    unsigned word = 0; int pc = 0, pre = 0;
    if (tid < 128) {                       // popc prefix scan of 128 words
        word = bitmap[n * NWORDS + tid];
        pc = __popc(word);
        pre = pc;
        #pragma unroll
        for (int off = 1; off < 64; off <<= 1) {
            int u = __shfl_up(pre, off, 64);
            if ((tid & 63) >= off) pre += u;
        }
        if ((tid & 63) == 63) wsum[tid >> 6] = pre;
    }
    __syncthreads();
    if (tid < 128) {
        int base = (tid >= 64) ? wsum[0] : 0;
        int off = base + pre - pc;
        while (word) {
            int bit = __ffs(word) - 1;
            word &= word - 1;
            if (off < MAXC) sIdx[off] = (tid << 5) + bit;
            ++off;
        }
        if (tid == 127) scnt = min(base + pre, MAXC);
    }
    __syncthreads();
    int c = scnt;

    const unsigned short* kbase = kh + ((size_t)h * N_NODES << 5);
    const unsigned short* vbase = vh + ((size_t)h * N_NODES << 5) + lane;
    const float sc = 0.17677669529663687f;   // 1/sqrt(32)
    float m_run = -INFINITY, S = 0.0f, acc = 0.0f;
    for (int b0 = 0; b0 < c; b0 += 32) {
        int j = b0 + lane;
        float s = -INFINITY;
        if (j < c) {
            const unsigned short* kp = kbase + ((size_t)sIdx[j] << 5);
            float d = 0.0f;
            #pragma unroll
            for (int i = 0; i < 4; ++i) {
                short8 k8 = *(const short8*)(kp + i * 8);
                #pragma unroll
                for (int e = 0; e < 8; ++e)
                    d = fmaf(qreg[i * 8 + e], b2f((unsigned short)k8[e]), d);
            }
            s = d * sc;
        }
        float bm = s;
        #pragma unroll
        for (int off = 16; off; off >>= 1) bm = fmaxf(bm, __shfl_xor(bm, off, 32));
        float newM = fmaxf(m_run, bm);
        float p = (j < c) ? __expf(s - newM) : 0.0f;
        float bs = p;
        #pragma unroll
        for (int off = 16; off; off >>= 1) bs += __shfl_xor(bs, off, 32);
        float scale = __expf(m_run - newM);
        S = S * scale + bs;
        acc *= scale;
        int lim = min(32, c - b0);
        #pragma unroll 4
        for (int jj = 0; jj < lim; ++jj) {
            float pj = __shfl(p, jj, 32);
            int m = sIdx[b0 + jj];
            acc = fmaf(pj, b2f(vbase[(size_t)m << 5]), acc);
        }
        m_run = newM;
    }
    y[(size_t)n * 256 + h * 32 + lane] = f2b(acc / S);
}

extern "C" void kernel_launch(void* const* d_in, const int* in_sizes, int n_in,
                              void* d_out, int out_size, void* d_ws, size_t ws_size,
                              hipStream_t stream) {
    const float* x   = (const float*)d_in[0];
    const int*   ei  = (const int*)d_in[1];
    const float* Wq  = (const float*)d_in[2];  const float* bq  = (const float*)d_in[3];
    const float* Wk  = (const float*)d_in[4];  const float* bk  = (const float*)d_in[5];
    const float* Wv  = (const float*)d_in[6];  const float* bv  = (const float*)d_in[7];
    const float* Wo  = (const float*)d_in[8];  const float* bo  = (const float*)d_in[9];
    const float* g1  = (const float*)d_in[10]; const float* b1  = (const float*)d_in[11];
    const float* g2  = (const float*)d_in[12]; const float* b2  = (const float*)d_in[13];
    const float* Wm1 = (const float*)d_in[14]; const float* bm1 = (const float*)d_in[15];
    const float* Wm2 = (const float*)d_in[16]; const float* bm2 = (const float*)d_in[17];
    float* out = (float*)d_out;
    int E = in_sizes[1] / 2;   // 135168
    int nadj = (E + 511) / 512;

    char* WS = (char*)d_ws;
    const size_t MB = 1u << 20;
    unsigned*       bitmap = (unsigned*)WS;                        // [0,2MB)
    int*            flag   = (int*)(WS + 2 * MB);                  // 4B
    float*          psum   = (float*)(WS + 2 * MB + 4096);         // 64KB [N][4]
    float*          psum2  = (float*)(WS + 2 * MB + 4096 + 65536); // 64KB
    unsigned short* wbf    = (unsigned short*)(WS + 3 * MB);       // 1MB
    unsigned short* y      = (unsigned short*)(WS + 4 * MB);       // 2MB
    float*          x1     = (float*)(WS + 6 * MB);                // 4MB
    unsigned short* m1     = (unsigned short*)(WS + 10 * MB);      // 4MB
    unsigned short* h      = (unsigned short*)(WS + 14 * MB);      // 2MB
    unsigned short* qh     = (unsigned short*)(WS + 16 * MB);      // 2MB [8][N][32]
    unsigned short* kh     = (unsigned short*)(WS + 18 * MB);      // 2MB
    unsigned short* vh     = (unsigned short*)(WS + 20 * MB);      // 2MB

    const unsigned short* WTqkv = wbf;            // q|k|v stacked along M
    const unsigned short* WTo   = wbf + 196608;
    const unsigned short* WTm1  = wbf + 262144;
    const unsigned short* WTm2  = wbf + 393216;

    // 1) convw + zero bitmap + detect + LN1
    prep_kernel<<<6657, 256, 0, stream>>>(Wq, Wk, Wv, Wo, Wm1, Wm2, wbf,
                                          (uint4*)bitmap, ei, flag, x, g1, b1, h);
    // 2) build_adj (blocks [0,nadj)) + qkv GEMM, head-major stores
    gemm_bf16<256, 3, false, false><<<nadj + 768, 512, 0, stream>>>(h, nullptr,
            nullptr, nullptr, nullptr, nullptr, WTqkv, bq, bk, bv, nullptr,
            nullptr, qh, kh, vh, nullptr, nullptr, 768, ei, E, flag, bitmap, nadj);
    // 3) attention
    attn_kernel<<<N_NODES, 256, 0, stream>>>(qh, kh, vh, bitmap, y);
    // 4) x1 = x + y @ Wo + bo   (+ per-row partial LN2 stats)
    gemm_bf16<256, 2, false, true><<<dim3(64, 4), 512, 0, stream>>>(y, nullptr,
            nullptr, nullptr, nullptr, nullptr, WTo, bo, nullptr, nullptr, x,
            x1, nullptr, nullptr, nullptr, psum, psum2, 256, nullptr, 0, nullptr, nullptr, 0);
    // 5) m1 = gelu(LN2(x1) @ Wm1 + bm1)   (LN2 applied during A-staging)
    gemm_bf16<256, 1, true, false><<<dim3(64, 8), 512, 0, stream>>>(nullptr, x1,
            psum, psum2, g2, b2, WTm1, bm1, nullptr, nullptr, nullptr,
            nullptr, m1, nullptr, nullptr, nullptr, nullptr, 512, nullptr, 0, nullptr, nullptr, 0);
    // 6) out = x1 + m1 @ Wm2 + bm2
    gemm_bf16<512, 2, false, false><<<dim3(64, 4), 512, 0, stream>>>(m1, nullptr,
            nullptr, nullptr, nullptr, nullptr, WTm2, bm2, nullptr, nullptr, x1,
            out, nullptr, nullptr, nullptr, nullptr, nullptr, 256, nullptr, 0, nullptr, nullptr, 0);
}

// Round 13
// 81.997 us; speedup vs baseline: 3.7981x; 1.0514x over previous
//
#include <hip/hip_runtime.h>
#include <hip/hip_bf16.h>

#define N_NODES 4096
#define D_MODEL 256
#define NWORDS 128   // bitmap words per row (4096/32)
#define CAP 256      // max neighbors per row (avg ~33; 256 is >30 sigma)

typedef __attribute__((ext_vector_type(8))) short short8;
typedef __attribute__((ext_vector_type(4))) float f32x4;

__device__ __forceinline__ unsigned short f2b(float f) {  // fp32 -> bf16 RTN
    unsigned u = __float_as_uint(f);
    return (unsigned short)((u + 0x7FFFu + ((u >> 16) & 1u)) >> 16);
}
__device__ __forceinline__ float b2f(unsigned short u) {
    return __uint_as_float((unsigned)u << 16);
}

// ---- prep: convw (0..2047) | zero bitmap (2048..2559) | detect (2560)
// ----       | LN1 rows (2561..6656) ---------------------------------------
__global__ __launch_bounds__(256) void prep_kernel(const float* __restrict__ Wq,
        const float* __restrict__ Wk, const float* __restrict__ Wv,
        const float* __restrict__ Wo, const float* __restrict__ Wm1,
        const float* __restrict__ Wm2, unsigned short* __restrict__ wbf,
        uint4* __restrict__ bitmap, const int* __restrict__ ei,
        int* __restrict__ flag, const float* __restrict__ x,
        const float* __restrict__ g1, const float* __restrict__ b1,
        unsigned short* __restrict__ h) {
    int b = blockIdx.x, t = threadIdx.x;
    if (b < 2048) {                       // weight fp32 [K][M] -> bf16 [M][K]
        int e = b * 256 + t;              // 0..524287
        const float* W; int base, K, M;
        if (e < 262144) {
            int r = e >> 16;
            W = (r == 0) ? Wq : (r == 1) ? Wk : (r == 2) ? Wv : Wo;
            base = r << 16; K = 256; M = 256;
        } else if (e < 393216) { W = Wm1; base = 262144; K = 256; M = 512; }
        else                   { W = Wm2; base = 393216; K = 512; M = 256; }
        int i = e - base;
        int m = i / K, k = i - m * K;
        wbf[e] = f2b(W[k * M + m]);
    } else if (b < 2560) {                // zero the 2MB bitmap
        bitmap[(size_t)(b - 2048) * 256 + t] = uint4{0, 0, 0, 0};
    } else if (b == 2560) {               // edge dtype detect
        if (t == 0) {
            int is64 = 1;
            for (int i = 1; i < 128; i += 2)
                if (ei[i] != 0) { is64 = 0; break; }
            *flag = is64;
        }
    } else {                              // LayerNorm1: one row per block
        int row = b - 2561;
        float v = x[row * D_MODEL + t];
        __shared__ float red[4];
        float s = v;
        #pragma unroll
        for (int off = 32; off; off >>= 1) s += __shfl_down(s, off, 64);
        if ((t & 63) == 0) red[t >> 6] = s;
        __syncthreads();
        float mu = (red[0] + red[1] + red[2] + red[3]) * (1.0f / 256.0f);
        __syncthreads();
        float d = v - mu;
        float s2 = d * d;
        #pragma unroll
        for (int off = 32; off; off >>= 1) s2 += __shfl_down(s2, off, 64);
        if ((t & 63) == 0) red[t >> 6] = s2;
        __syncthreads();
        float var = (red[0] + red[1] + red[2] + red[3]) * (1.0f / 256.0f);
        h[row * D_MODEL + t] = f2b(d * rsqrtf(var + 1e-5f) * g1[t] + b1[t]);
    }
}

// ---- bf16 MFMA GEMM: 64x64 tile, 512 thr / 8 waves, BK=64 ----------------
// MODE 1: +bias,GELU -> bf16 | 2: +bias+R -> f32 | 3: qkv 3-part bias,
//   head-major stores q/k/v[h][N][32] (+ build_adj in blocks [0,nadj))
// LNA:   A is f32 + per-row partial stats -> layernorm during A-staging
// STATS: epilogue emits per-row partial sum/sumsq of C (for downstream LN)
template <int K, int MODE, bool LNA, bool STATS>
__global__ __launch_bounds__(512) void gemm_bf16(const unsigned short* __restrict__ A,
        const float* __restrict__ Af, const float* __restrict__ psum,
        const float* __restrict__ psum2, const float* __restrict__ lng,
        const float* __restrict__ lnb, const unsigned short* __restrict__ BT,
        const float* __restrict__ bias, const float* __restrict__ bias_k,
        const float* __restrict__ bias_v, const float* __restrict__ R,
        float* __restrict__ Cf, unsigned short* __restrict__ Cb,
        unsigned short* __restrict__ Ck, unsigned short* __restrict__ Cv,
        float* __restrict__ opsum, float* __restrict__ opsum2, int M,
        const int* __restrict__ ei, int E, const int* __restrict__ flag,
        unsigned* __restrict__ bitmap, int nadj) {
    int tid = threadIdx.x;
    if (MODE == 3 && (int)blockIdx.x < nadj) {   // fused edge scatter
        int e = (int)blockIdx.x * 512 + tid;
        if (e < E) {
            int n, m;
            if (*flag) { n = ei[2 * e]; m = ei[2 * (E + e)]; }
            else       { n = ei[e];     m = ei[E + e]; }
            atomicOr(&bitmap[n * NWORDS + (m >> 5)], 1u << (m & 31));
        }
        return;
    }
    __shared__ unsigned short Asm[64][72];
    __shared__ unsigned short Bsm[64][72];
    __shared__ float psA[64][2], psA2[64][2];
    __shared__ float muS[64], invS[64];

    int bx2  = (MODE == 3) ? ((int)blockIdx.x - nadj) : 0;
    int brow = (MODE == 3) ? ((bx2 & 63) << 6) : ((int)blockIdx.x << 6);
    int by   = (MODE == 3) ? (bx2 >> 6) : (int)blockIdx.y;
    int bcol = by << 6;
    int wid = tid >> 6, lane = tid & 63;
    int wr = wid >> 1, wc = wid & 1;             // 4 row-waves x 2 col-waves
    int l15 = lane & 15, lhi = lane >> 4;
    int r0 = tid >> 3, c0 = (tid & 7) << 3;

    float mu_r = 0.f, inv_r = 0.f;
    if (LNA) {   // combine partial stats once per block
        if (tid < 64) {
            float4 s4 = ((const float4*)psum)[brow + tid];
            float4 q4 = ((const float4*)psum2)[brow + tid];
            float S  = s4.x + s4.y + s4.z + s4.w;
            float S2 = q4.x + q4.y + q4.z + q4.w;
            float mu = S * (1.0f / 256.0f);
            muS[tid] = mu;
            invS[tid] = rsqrtf(S2 * (1.0f / 256.0f) - mu * mu + 1e-5f);
        }
        __syncthreads();
        mu_r = muS[r0]; inv_r = invS[r0];
    }

    const unsigned short* Bp = BT + (size_t)(bcol + r0) * K + c0;
    f32x4 acc[2] = {};
    short8 areg;
    float4 xa, xb, ga, gb, ba, bb;
    if (LNA) {
        const float* Xp = Af + (size_t)(brow + r0) * 256 + c0;
        xa = *(const float4*)(Xp);
        xb = *(const float4*)(Xp + 4);
        ga = *(const float4*)(lng + c0); gb = *(const float4*)(lng + c0 + 4);
        ba = *(const float4*)(lnb + c0); bb = *(const float4*)(lnb + c0 + 4);
    } else {
        areg = *(const short8*)(A + (size_t)(brow + r0) * K + c0);
    }
    short8 breg = *(const short8*)(Bp);

    #pragma unroll
    for (int k0 = 0; k0 < K; k0 += 64) {
        if (LNA) {   // layernorm on the fly into LDS
            float xv[8] = {xa.x, xa.y, xa.z, xa.w, xb.x, xb.y, xb.z, xb.w};
            float gv[8] = {ga.x, ga.y, ga.z, ga.w, gb.x, gb.y, gb.z, gb.w};
            float bv[8] = {ba.x, ba.y, ba.z, ba.w, bb.x, bb.y, bb.z, bb.w};
            short8 o;
            #pragma unroll
            for (int j = 0; j < 8; ++j)
                o[j] = (short)f2b((xv[j] - mu_r) * inv_r * gv[j] + bv[j]);
            *(short8*)&Asm[r0][c0] = o;
        } else {
            *(short8*)&Asm[r0][c0] = areg;
        }
        *(short8*)&Bsm[r0][c0] = breg;
        __syncthreads();
        if (k0 + 64 < K) {                      // prefetch next K-step
            if (LNA) {
                const float* Xp = Af + (size_t)(brow + r0) * 256 + k0 + 64 + c0;
                xa = *(const float4*)(Xp);
                xb = *(const float4*)(Xp + 4);
                ga = *(const float4*)(lng + k0 + 64 + c0);
                gb = *(const float4*)(lng + k0 + 64 + c0 + 4);
                ba = *(const float4*)(lnb + k0 + 64 + c0);
                bb = *(const float4*)(lnb + k0 + 64 + c0 + 4);
            } else {
                areg = *(const short8*)(A + (size_t)(brow + r0) * K + k0 + 64 + c0);
            }
            breg = *(const short8*)(Bp + k0 + 64);
        }
        #pragma unroll
        for (int ks = 0; ks < 2; ++ks) {
            int kc = ks * 32 + lhi * 8;
            short8 a_0 = *(const short8*)&Asm[wr * 16 + l15][kc];
            short8 b_0 = *(const short8*)&Bsm[wc * 32 + l15][kc];
            short8 b_1 = *(const short8*)&Bsm[wc * 32 + 16 + l15][kc];
            acc[0] = __builtin_amdgcn_mfma_f32_16x16x32_bf16(a_0, b_0, acc[0], 0, 0, 0);
            acc[1] = __builtin_amdgcn_mfma_f32_16x16x32_bf16(a_0, b_1, acc[1], 0, 0, 0);
        }
        __syncthreads();
    }

    float cs[2][4];
    #pragma unroll
    for (int sn = 0; sn < 2; ++sn) {
        int col = bcol + wc * 32 + sn * 16 + l15;
        float bs;
        if (MODE == 3)
            bs = (col < 256) ? bias[col]
               : (col < 512) ? bias_k[col - 256] : bias_v[col - 512];
        else
            bs = bias[col];
        #pragma unroll
        for (int r = 0; r < 4; ++r) {
            int row = brow + wr * 16 + lhi * 4 + r;
            float c = acc[sn][r] + bs;
            if (MODE == 1) {
                c = 0.5f * c * (1.0f + erff(c * 0.70710678118654752f));
                Cb[(size_t)row * M + col] = f2b(c);
            } else if (MODE == 2) {
                c += R[(size_t)row * M + col];
                Cf[(size_t)row * M + col] = c;
            } else if (MODE == 3) {
                // head-major: part (q/k/v), head = cc>>5, dim = cc&31
                int part = col >> 8, cc = col & 255;
                unsigned short* dst = (part == 0) ? Cb : (part == 1) ? Ck : Cv;
                dst[(((size_t)(cc >> 5) * N_NODES + row) << 5) + (cc & 31)] = f2b(c);
            } else {
                Cb[(size_t)row * M + col] = f2b(c);
            }
            if (STATS) cs[sn][r] = c;
        }
    }
    if (STATS) {   // deterministic per-row partial stats over this 64-col strip
        #pragma unroll
        for (int r = 0; r < 4; ++r) {
            float s  = cs[0][r] + cs[1][r];
            float s2 = cs[0][r] * cs[0][r] + cs[1][r] * cs[1][r];
            #pragma unroll
            for (int off = 1; off < 16; off <<= 1) {
                s  += __shfl_xor(s, off, 64);
                s2 += __shfl_xor(s2, off, 64);
            }
            if (l15 == 0) {
                int rl = wr * 16 + lhi * 4 + r;
                psA[rl][wc] = s; psA2[rl][wc] = s2;
            }
        }
        __syncthreads();
        if (tid < 64) {
            opsum [(size_t)(brow + tid) * 4 + by] = psA[tid][0] + psA[tid][1];
            opsum2[(size_t)(brow + tid) * 4 + by] = psA2[tid][0] + psA2[tid][1];
        }
    }
}

// ---------------- sparse attention, XCD-pinned heads -----------------------
// block = 8 rows x 1 head (8 groups of 32 lanes); head = blockIdx.x & 7 so
// each XCD (round-robin dispatch) touches ONE head's dense q/k/v (3x256KB)
// + the shared bitmap (2MB) = 2.75MB < 4MB per-XCD L2 -> gathers hit L2.
__global__ __launch_bounds__(256) void attn_kernel(const unsigned short* __restrict__ qh,
        const unsigned short* __restrict__ kh, const unsigned short* __restrict__ vh,
        const unsigned* __restrict__ bitmap, unsigned short* __restrict__ y) {
    int bid = blockIdx.x, tid = threadIdx.x;
    int h = bid & 7, oct = bid >> 3;
    int g = tid >> 5, lane = tid & 31;
    int n = oct * 8 + g;
    __shared__ int sIdx[8][CAP];

    // q load first: latency hides under the bitmap scan
    const unsigned short* qp = qh + (((size_t)h * N_NODES + n) << 5);
    float qreg[32];
    #pragma unroll
    for (int i = 0; i < 4; ++i) {
        short8 q8 = *(const short8*)(qp + i * 8);
        #pragma unroll
        for (int j = 0; j < 8; ++j) qreg[i * 8 + j] = b2f((unsigned short)q8[j]);
    }

    // group-local bitmap scan: lane holds 4 words (uint4 = its 16B slice)
    uint4 w4 = ((const uint4*)(bitmap + (size_t)n * NWORDS))[lane];
    unsigned words[4] = {w4.x, w4.y, w4.z, w4.w};
    int pc = __popc(w4.x) + __popc(w4.y) + __popc(w4.z) + __popc(w4.w);
    int pre = pc;
    #pragma unroll
    for (int off = 1; off < 32; off <<= 1) {
        int u = __shfl_up(pre, off, 32);
        if (lane >= off) pre += u;
    }
    int c = __shfl(pre, 31, 32);          // row neighbor count
    int off = pre - pc;                   // exclusive prefix
    #pragma unroll
    for (int i = 0; i < 4; ++i) {
        unsigned word = words[i];
        int wbase = ((lane << 2) + i) << 5;
        while (word) {
            int bit = __ffs(word) - 1;
            word &= word - 1;
            if (off < CAP) sIdx[g][off] = wbase + bit;
            ++off;
        }
    }
    c = min(c, CAP);
    __syncthreads();

    const unsigned short* kbase = kh + ((size_t)h * N_NODES << 5);
    const unsigned short* vbase = vh + ((size_t)h * N_NODES << 5) + lane;
    const float sc = 0.17677669529663687f;   // 1/sqrt(32)
    float m_run = -INFINITY, S = 0.0f, acc = 0.0f;
    for (int b0 = 0; b0 < c; b0 += 32) {
        int j = b0 + lane;
        float s = -INFINITY;
        if (j < c) {
            const unsigned short* kp = kbase + ((size_t)sIdx[g][j] << 5);
            float d = 0.0f;
            #pragma unroll
            for (int i = 0; i < 4; ++i) {
                short8 k8 = *(const short8*)(kp + i * 8);
                #pragma unroll
                for (int e = 0; e < 8; ++e)
                    d = fmaf(qreg[i * 8 + e], b2f((unsigned short)k8[e]), d);
            }
            s = d * sc;
        }
        float bm = s;
        #pragma unroll
        for (int off2 = 16; off2; off2 >>= 1) bm = fmaxf(bm, __shfl_xor(bm, off2, 32));
        float newM = fmaxf(m_run, bm);
        float p = (j < c) ? __expf(s - newM) : 0.0f;
        float bs = p;
        #pragma unroll
        for (int off2 = 16; off2; off2 >>= 1) bs += __shfl_xor(bs, off2, 32);
        float scale = __expf(m_run - newM);
        S = S * scale + bs;
        acc *= scale;
        int lim = min(32, c - b0);
        #pragma unroll 4
        for (int jj = 0; jj < lim; ++jj) {
            float pj = __shfl(p, jj, 32);
            int m = sIdx[g][b0 + jj];
            acc = fmaf(pj, b2f(vbase[(size_t)m << 5]), acc);
        }
        m_run = newM;
    }
    y[(size_t)n * 256 + h * 32 + lane] = f2b(acc / S);
}

extern "C" void kernel_launch(void* const* d_in, const int* in_sizes, int n_in,
                              void* d_out, int out_size, void* d_ws, size_t ws_size,
                              hipStream_t stream) {
    const float* x   = (const float*)d_in[0];
    const int*   ei  = (const int*)d_in[1];
    const float* Wq  = (const float*)d_in[2];  const float* bq  = (const float*)d_in[3];
    const float* Wk  = (const float*)d_in[4];  const float* bk  = (const float*)d_in[5];
    const float* Wv  = (const float*)d_in[6];  const float* bv  = (const float*)d_in[7];
    const float* Wo  = (const float*)d_in[8];  const float* bo  = (const float*)d_in[9];
    const float* g1  = (const float*)d_in[10]; const float* b1  = (const float*)d_in[11];
    const float* g2  = (const float*)d_in[12]; const float* b2  = (const float*)d_in[13];
    const float* Wm1 = (const float*)d_in[14]; const float* bm1 = (const float*)d_in[15];
    const float* Wm2 = (const float*)d_in[16]; const float* bm2 = (const float*)d_in[17];
    float* out = (float*)d_out;
    int E = in_sizes[1] / 2;   // 135168
    int nadj = (E + 511) / 512;

    char* WS = (char*)d_ws;
    const size_t MB = 1u << 20;
    unsigned*       bitmap = (unsigned*)WS;                        // [0,2MB)
    int*            flag   = (int*)(WS + 2 * MB);                  // 4B
    float*          psum   = (float*)(WS + 2 * MB + 4096);         // 64KB [N][4]
    float*          psum2  = (float*)(WS + 2 * MB + 4096 + 65536); // 64KB
    unsigned short* wbf    = (unsigned short*)(WS + 3 * MB);       // 1MB
    unsigned short* y      = (unsigned short*)(WS + 4 * MB);       // 2MB
    float*          x1     = (float*)(WS + 6 * MB);                // 4MB
    unsigned short* m1     = (unsigned short*)(WS + 10 * MB);      // 4MB
    unsigned short* h      = (unsigned short*)(WS + 14 * MB);      // 2MB
    unsigned short* qh     = (unsigned short*)(WS + 16 * MB);      // 2MB [8][N][32]
    unsigned short* kh     = (unsigned short*)(WS + 18 * MB);      // 2MB
    unsigned short* vh     = (unsigned short*)(WS + 20 * MB);      // 2MB

    const unsigned short* WTqkv = wbf;            // q|k|v stacked along M
    const unsigned short* WTo   = wbf + 196608;
    const unsigned short* WTm1  = wbf + 262144;
    const unsigned short* WTm2  = wbf + 393216;

    // 1) convw + zero bitmap + detect + LN1
    prep_kernel<<<6657, 256, 0, stream>>>(Wq, Wk, Wv, Wo, Wm1, Wm2, wbf,
                                          (uint4*)bitmap, ei, flag, x, g1, b1, h);
    // 2) build_adj (blocks [0,nadj)) + qkv GEMM, head-major stores
    gemm_bf16<256, 3, false, false><<<nadj + 768, 512, 0, stream>>>(h, nullptr,
            nullptr, nullptr, nullptr, nullptr, WTqkv, bq, bk, bv, nullptr,
            nullptr, qh, kh, vh, nullptr, nullptr, 768, ei, E, flag, bitmap, nadj);
    // 3) attention (XCD-pinned heads: head = bid & 7)
    attn_kernel<<<N_NODES, 256, 0, stream>>>(qh, kh, vh, bitmap, y);
    // 4) x1 = x + y @ Wo + bo   (+ per-row partial LN2 stats)
    gemm_bf16<256, 2, false, true><<<dim3(64, 4), 512, 0, stream>>>(y, nullptr,
            nullptr, nullptr, nullptr, nullptr, WTo, bo, nullptr, nullptr, x,
            x1, nullptr, nullptr, nullptr, psum, psum2, 256, nullptr, 0, nullptr, nullptr, 0);
    // 5) m1 = gelu(LN2(x1) @ Wm1 + bm1)   (LN2 applied during A-staging)
    gemm_bf16<256, 1, true, false><<<dim3(64, 8), 512, 0, stream>>>(nullptr, x1,
            psum, psum2, g2, b2, WTm1, bm1, nullptr, nullptr, nullptr,
            nullptr, m1, nullptr, nullptr, nullptr, nullptr, 512, nullptr, 0, nullptr, nullptr, 0);
    // 6) out = x1 + m1 @ Wm2 + bm2
    gemm_bf16<512, 2, false, false><<<dim3(64, 4), 512, 0, stream>>>(m1, nullptr,
            nullptr, nullptr, nullptr, nullptr, WTm2, bm2, nullptr, nullptr, x1,
            out, nullptr, nullptr, nullptr, nullptr, nullptr, 256, nullptr, 0, nullptr, nullptr, 0);
}

// Round 14
// 75.084 us; speedup vs baseline: 4.1478x; 1.0921x over previous
//
#include <hip/hip_runtime.h>
#include <hip/hip_bf16.h>

#define N_NODES 4096
#define D_MODEL 256
#define NWORDS 128   // bitmap words per row (4096/32)
#define CAP 128      // max neighbors per row (avg ~33; 128 is astronomically safe)

typedef __attribute__((ext_vector_type(8))) short short8;
typedef __attribute__((ext_vector_type(4))) float f32x4;

__device__ __forceinline__ unsigned short f2b(float f) {  // fp32 -> bf16 RTN
    unsigned u = __float_as_uint(f);
    return (unsigned short)((u + 0x7FFFu + ((u >> 16) & 1u)) >> 16);
}
__device__ __forceinline__ float b2f(unsigned short u) {
    return __uint_as_float((unsigned)u << 16);
}

// ---- prep: convw (0..2047) | zero bitmap (2048..2559) | detect (2560)
// ----       | LN1 rows (2561..6656) ---------------------------------------
__global__ __launch_bounds__(256) void prep_kernel(const float* __restrict__ Wq,
        const float* __restrict__ Wk, const float* __restrict__ Wv,
        const float* __restrict__ Wo, const float* __restrict__ Wm1,
        const float* __restrict__ Wm2, unsigned short* __restrict__ wbf,
        uint4* __restrict__ bitmap, const int* __restrict__ ei,
        int* __restrict__ flag, const float* __restrict__ x,
        const float* __restrict__ g1, const float* __restrict__ b1,
        unsigned short* __restrict__ h) {
    int b = blockIdx.x, t = threadIdx.x;
    if (b < 2048) {                       // weight fp32 [K][M] -> bf16 [M][K]
        int e = b * 256 + t;              // 0..524287
        const float* W; int base, K, M;
        if (e < 262144) {
            int r = e >> 16;
            W = (r == 0) ? Wq : (r == 1) ? Wk : (r == 2) ? Wv : Wo;
            base = r << 16; K = 256; M = 256;
        } else if (e < 393216) { W = Wm1; base = 262144; K = 256; M = 512; }
        else                   { W = Wm2; base = 393216; K = 512; M = 256; }
        int i = e - base;
        int m = i / K, k = i - m * K;
        wbf[e] = f2b(W[k * M + m]);
    } else if (b < 2560) {                // zero the 2MB bitmap
        bitmap[(size_t)(b - 2048) * 256 + t] = uint4{0, 0, 0, 0};
    } else if (b == 2560) {               // edge dtype detect
        if (t == 0) {
            int is64 = 1;
            for (int i = 1; i < 128; i += 2)
                if (ei[i] != 0) { is64 = 0; break; }
            *flag = is64;
        }
    } else {                              // LayerNorm1: one row per block
        int row = b - 2561;
        float v = x[row * D_MODEL + t];
        __shared__ float red[4];
        float s = v;
        #pragma unroll
        for (int off = 32; off; off >>= 1) s += __shfl_down(s, off, 64);
        if ((t & 63) == 0) red[t >> 6] = s;
        __syncthreads();
        float mu = (red[0] + red[1] + red[2] + red[3]) * (1.0f / 256.0f);
        __syncthreads();
        float d = v - mu;
        float s2 = d * d;
        #pragma unroll
        for (int off = 32; off; off >>= 1) s2 += __shfl_down(s2, off, 64);
        if ((t & 63) == 0) red[t >> 6] = s2;
        __syncthreads();
        float var = (red[0] + red[1] + red[2] + red[3]) * (1.0f / 256.0f);
        h[row * D_MODEL + t] = f2b(d * rsqrtf(var + 1e-5f) * g1[t] + b1[t]);
    }
}

// ---- bf16 MFMA GEMM: 64x64 tile, 512 thr / 8 waves, BK=64 ----------------
// MODE 1: +bias,GELU -> bf16 | 2: +bias+R -> f32 | 3: qkv 3-part bias,
//   head-major stores q/k/v[h][N][32] (+ build_adj in blocks [0,nadj))
// LNA:   A is f32 + per-row partial stats -> layernorm during A-staging
// STATS: epilogue emits per-row partial sum/sumsq of C (for downstream LN)
template <int K, int MODE, bool LNA, bool STATS>
__global__ __launch_bounds__(512) void gemm_bf16(const unsigned short* __restrict__ A,
        const float* __restrict__ Af, const float* __restrict__ psum,
        const float* __restrict__ psum2, const float* __restrict__ lng,
        const float* __restrict__ lnb, const unsigned short* __restrict__ BT,
        const float* __restrict__ bias, const float* __restrict__ bias_k,
        const float* __restrict__ bias_v, const float* __restrict__ R,
        float* __restrict__ Cf, unsigned short* __restrict__ Cb,
        unsigned short* __restrict__ Ck, unsigned short* __restrict__ Cv,
        float* __restrict__ opsum, float* __restrict__ opsum2, int M,
        const int* __restrict__ ei, int E, const int* __restrict__ flag,
        unsigned* __restrict__ bitmap, int nadj) {
    int tid = threadIdx.x;
    if (MODE == 3 && (int)blockIdx.x < nadj) {   // fused edge scatter
        int e = (int)blockIdx.x * 512 + tid;
        if (e < E) {
            int n, m;
            if (*flag) { n = ei[2 * e]; m = ei[2 * (E + e)]; }
            else       { n = ei[e];     m = ei[E + e]; }
            atomicOr(&bitmap[n * NWORDS + (m >> 5)], 1u << (m & 31));
        }
        return;
    }
    __shared__ unsigned short Asm[64][72];
    __shared__ unsigned short Bsm[64][72];
    __shared__ float psA[64][2], psA2[64][2];
    __shared__ float muS[64], invS[64];

    int bx2  = (MODE == 3) ? ((int)blockIdx.x - nadj) : 0;
    int brow = (MODE == 3) ? ((bx2 & 63) << 6) : ((int)blockIdx.x << 6);
    int by   = (MODE == 3) ? (bx2 >> 6) : (int)blockIdx.y;
    int bcol = by << 6;
    int wid = tid >> 6, lane = tid & 63;
    int wr = wid >> 1, wc = wid & 1;             // 4 row-waves x 2 col-waves
    int l15 = lane & 15, lhi = lane >> 4;
    int r0 = tid >> 3, c0 = (tid & 7) << 3;

    float mu_r = 0.f, inv_r = 0.f;
    if (LNA) {   // combine partial stats once per block
        if (tid < 64) {
            float4 s4 = ((const float4*)psum)[brow + tid];
            float4 q4 = ((const float4*)psum2)[brow + tid];
            float S  = s4.x + s4.y + s4.z + s4.w;
            float S2 = q4.x + q4.y + q4.z + q4.w;
            float mu = S * (1.0f / 256.0f);
            muS[tid] = mu;
            invS[tid] = rsqrtf(S2 * (1.0f / 256.0f) - mu * mu + 1e-5f);
        }
        __syncthreads();
        mu_r = muS[r0]; inv_r = invS[r0];
    }

    const unsigned short* Bp = BT + (size_t)(bcol + r0) * K + c0;
    f32x4 acc[2] = {};
    short8 areg;
    float4 xa, xb, ga, gb, ba, bb;
    if (LNA) {
        const float* Xp = Af + (size_t)(brow + r0) * 256 + c0;
        xa = *(const float4*)(Xp);
        xb = *(const float4*)(Xp + 4);
        ga = *(const float4*)(lng + c0); gb = *(const float4*)(lng + c0 + 4);
        ba = *(const float4*)(lnb + c0); bb = *(const float4*)(lnb + c0 + 4);
    } else {
        areg = *(const short8*)(A + (size_t)(brow + r0) * K + c0);
    }
    short8 breg = *(const short8*)(Bp);

    #pragma unroll
    for (int k0 = 0; k0 < K; k0 += 64) {
        if (LNA) {   // layernorm on the fly into LDS
            float xv[8] = {xa.x, xa.y, xa.z, xa.w, xb.x, xb.y, xb.z, xb.w};
            float gv[8] = {ga.x, ga.y, ga.z, ga.w, gb.x, gb.y, gb.z, gb.w};
            float bv[8] = {ba.x, ba.y, ba.z, ba.w, bb.x, bb.y, bb.z, bb.w};
            short8 o;
            #pragma unroll
            for (int j = 0; j < 8; ++j)
                o[j] = (short)f2b((xv[j] - mu_r) * inv_r * gv[j] + bv[j]);
            *(short8*)&Asm[r0][c0] = o;
        } else {
            *(short8*)&Asm[r0][c0] = areg;
        }
        *(short8*)&Bsm[r0][c0] = breg;
        __syncthreads();
        if (k0 + 64 < K) {                      // prefetch next K-step
            if (LNA) {
                const float* Xp = Af + (size_t)(brow + r0) * 256 + k0 + 64 + c0;
                xa = *(const float4*)(Xp);
                xb = *(const float4*)(Xp + 4);
                ga = *(const float4*)(lng + k0 + 64 + c0);
                gb = *(const float4*)(lng + k0 + 64 + c0 + 4);
                ba = *(const float4*)(lnb + k0 + 64 + c0);
                bb = *(const float4*)(lnb + k0 + 64 + c0 + 4);
            } else {
                areg = *(const short8*)(A + (size_t)(brow + r0) * K + k0 + 64 + c0);
            }
            breg = *(const short8*)(Bp + k0 + 64);
        }
        #pragma unroll
        for (int ks = 0; ks < 2; ++ks) {
            int kc = ks * 32 + lhi * 8;
            short8 a_0 = *(const short8*)&Asm[wr * 16 + l15][kc];
            short8 b_0 = *(const short8*)&Bsm[wc * 32 + l15][kc];
            short8 b_1 = *(const short8*)&Bsm[wc * 32 + 16 + l15][kc];
            acc[0] = __builtin_amdgcn_mfma_f32_16x16x32_bf16(a_0, b_0, acc[0], 0, 0, 0);
            acc[1] = __builtin_amdgcn_mfma_f32_16x16x32_bf16(a_0, b_1, acc[1], 0, 0, 0);
        }
        __syncthreads();
    }

    float cs[2][4];
    #pragma unroll
    for (int sn = 0; sn < 2; ++sn) {
        int col = bcol + wc * 32 + sn * 16 + l15;
        float bs;
        if (MODE == 3)
            bs = (col < 256) ? bias[col]
               : (col < 512) ? bias_k[col - 256] : bias_v[col - 512];
        else
            bs = bias[col];
        #pragma unroll
        for (int r = 0; r < 4; ++r) {
            int row = brow + wr * 16 + lhi * 4 + r;
            float c = acc[sn][r] + bs;
            if (MODE == 1) {
                c = 0.5f * c * (1.0f + erff(c * 0.70710678118654752f));
                Cb[(size_t)row * M + col] = f2b(c);
            } else if (MODE == 2) {
                c += R[(size_t)row * M + col];
                Cf[(size_t)row * M + col] = c;
            } else if (MODE == 3) {
                // head-major: part (q/k/v), head = cc>>5, dim = cc&31
                int part = col >> 8, cc = col & 255;
                unsigned short* dst = (part == 0) ? Cb : (part == 1) ? Ck : Cv;
                dst[(((size_t)(cc >> 5) * N_NODES + row) << 5) + (cc & 31)] = f2b(c);
            } else {
                Cb[(size_t)row * M + col] = f2b(c);
            }
            if (STATS) cs[sn][r] = c;
        }
    }
    if (STATS) {   // deterministic per-row partial stats over this 64-col strip
        #pragma unroll
        for (int r = 0; r < 4; ++r) {
            float s  = cs[0][r] + cs[1][r];
            float s2 = cs[0][r] * cs[0][r] + cs[1][r] * cs[1][r];
            #pragma unroll
            for (int off = 1; off < 16; off <<= 1) {
                s  += __shfl_xor(s, off, 64);
                s2 += __shfl_xor(s2, off, 64);
            }
            if (l15 == 0) {
                int rl = wr * 16 + lhi * 4 + r;
                psA[rl][wc] = s; psA2[rl][wc] = s2;
            }
        }
        __syncthreads();
        if (tid < 64) {
            opsum [(size_t)(brow + tid) * 4 + by] = psA[tid][0] + psA[tid][1];
            opsum2[(size_t)(brow + tid) * 4 + by] = psA2[tid][0] + psA2[tid][1];
        }
    }
}

// ---------------- sparse attention, XCD-pinned heads, single-pass ----------
// block = 8 rows x 1 head; head = blockIdx.x & 7 (XCD L2 pinning, r13-proven).
// New: c<=64 handled in ONE softmax pass (lane owns neighbors j and j+32) —
// no online rescale, no second K-batch issue. V rows staged to LDS early
// (loads issued before the K-dot so latency hides); PV reads LDS.
__global__ __launch_bounds__(256) void attn_kernel(const unsigned short* __restrict__ qh,
        const unsigned short* __restrict__ kh, const unsigned short* __restrict__ vh,
        const unsigned* __restrict__ bitmap, unsigned short* __restrict__ y) {
    int bid = blockIdx.x, tid = threadIdx.x;
    int h = bid & 7, oct = bid >> 3;
    int g = tid >> 5, lane = tid & 31;
    int n = oct * 8 + g;
    __shared__ int sIdx[8][CAP];
    __shared__ unsigned short Vst[8][64][36];   // stride 36 -> 2-way (free) banks

    // q load first: latency hides under the bitmap scan
    const unsigned short* qp = qh + (((size_t)h * N_NODES + n) << 5);
    float qreg[32];
    #pragma unroll
    for (int i = 0; i < 4; ++i) {
        short8 q8 = *(const short8*)(qp + i * 8);
        #pragma unroll
        for (int j = 0; j < 8; ++j) qreg[i * 8 + j] = b2f((unsigned short)q8[j]);
    }

    // group-local bitmap scan: lane holds 4 words (uint4 = its 16B slice)
    uint4 w4 = ((const uint4*)(bitmap + (size_t)n * NWORDS))[lane];
    unsigned words[4] = {w4.x, w4.y, w4.z, w4.w};
    int pc = __popc(w4.x) + __popc(w4.y) + __popc(w4.z) + __popc(w4.w);
    int pre = pc;
    #pragma unroll
    for (int off = 1; off < 32; off <<= 1) {
        int u = __shfl_up(pre, off, 32);
        if (lane >= off) pre += u;
    }
    int c = __shfl(pre, 31, 32);          // row neighbor count
    int off = pre - pc;                   // exclusive prefix
    #pragma unroll
    for (int i = 0; i < 4; ++i) {
        unsigned word = words[i];
        int wbase = ((lane << 2) + i) << 5;
        while (word) {
            int bit = __ffs(word) - 1;
            word &= word - 1;
            if (off < CAP) sIdx[g][off] = wbase + bit;
            ++off;
        }
    }
    c = min(c, CAP);
    for (int i = c + lane; i < 64; i += 32) sIdx[g][i] = 0;   // pad: safe index
    __syncthreads();

    int idx_a = sIdx[g][lane], idx_b = sIdx[g][lane + 32];
    const size_t hb = (size_t)h * N_NODES << 5;

    // issue V staging loads FIRST (latency hides under K gather + dot)
    const unsigned short* va = vh + hb + ((size_t)idx_a << 5);
    const unsigned short* vb = vh + hb + ((size_t)idx_b << 5);
    short8 va0 = *(const short8*)(va);      short8 va1 = *(const short8*)(va + 8);
    short8 va2 = *(const short8*)(va + 16); short8 va3 = *(const short8*)(va + 24);
    short8 vb0 = *(const short8*)(vb);      short8 vb1 = *(const short8*)(vb + 8);
    short8 vb2 = *(const short8*)(vb + 16); short8 vb3 = *(const short8*)(vb + 24);

    // K gather (issued after V; dot's wait drains V too)
    const unsigned short* ka = kh + hb + ((size_t)idx_a << 5);
    const unsigned short* kb = kh + hb + ((size_t)idx_b << 5);
    short8 ka0 = *(const short8*)(ka);      short8 ka1 = *(const short8*)(ka + 8);
    short8 ka2 = *(const short8*)(ka + 16); short8 ka3 = *(const short8*)(ka + 24);
    short8 kb0 = *(const short8*)(kb);      short8 kb1 = *(const short8*)(kb + 8);
    short8 kb2 = *(const short8*)(kb + 16); short8 kb3 = *(const short8*)(kb + 24);

    // stage V to LDS (waits only V loads; K still in flight)
    *(short8*)&Vst[g][lane][0]       = va0;
    *(short8*)&Vst[g][lane][8]       = va1;
    *(short8*)&Vst[g][lane][16]      = va2;
    *(short8*)&Vst[g][lane][24]      = va3;
    *(short8*)&Vst[g][lane + 32][0]  = vb0;
    *(short8*)&Vst[g][lane + 32][8]  = vb1;
    *(short8*)&Vst[g][lane + 32][16] = vb2;
    *(short8*)&Vst[g][lane + 32][24] = vb3;

    // dual dot with split chains for ILP
    float da0 = 0.f, da1 = 0.f, db0 = 0.f, db1 = 0.f;
    #pragma unroll
    for (int e = 0; e < 8; ++e) {
        da0 = fmaf(qreg[e],      b2f((unsigned short)ka0[e]), da0);
        da1 = fmaf(qreg[8 + e],  b2f((unsigned short)ka1[e]), da1);
        da0 = fmaf(qreg[16 + e], b2f((unsigned short)ka2[e]), da0);
        da1 = fmaf(qreg[24 + e], b2f((unsigned short)ka3[e]), da1);
        db0 = fmaf(qreg[e],      b2f((unsigned short)kb0[e]), db0);
        db1 = fmaf(qreg[8 + e],  b2f((unsigned short)kb1[e]), db1);
        db0 = fmaf(qreg[16 + e], b2f((unsigned short)kb2[e]), db0);
        db1 = fmaf(qreg[24 + e], b2f((unsigned short)kb3[e]), db1);
    }
    const float sc = 0.17677669529663687f;   // 1/sqrt(32)
    float s_a = (lane < c)      ? (da0 + da1) * sc : -INFINITY;
    float s_b = (lane + 32 < c) ? (db0 + db1) * sc : -INFINITY;

    // single-pass softmax over (up to) 64 neighbors
    float bm = fmaxf(s_a, s_b);
    #pragma unroll
    for (int o2 = 16; o2; o2 >>= 1) bm = fmaxf(bm, __shfl_xor(bm, o2, 32));
    float p_a = (lane < c)      ? __expf(s_a - bm) : 0.0f;
    float p_b = (lane + 32 < c) ? __expf(s_b - bm) : 0.0f;
    float S = p_a + p_b;
    #pragma unroll
    for (int o2 = 16; o2; o2 >>= 1) S += __shfl_xor(S, o2, 32);

    // PV from LDS (full unroll: ds_reads batch-issue)
    float acc0 = 0.f, acc1 = 0.f;
    #pragma unroll
    for (int jj = 0; jj < 32; ++jj) {
        float pa = __shfl(p_a, jj, 32);
        float pb = __shfl(p_b, jj, 32);
        acc0 = fmaf(pa, b2f(Vst[g][jj][lane]), acc0);
        acc1 = fmaf(pb, b2f(Vst[g][jj + 32][lane]), acc1);
    }
    float acc = acc0 + acc1;

    // rare fallback: rows with c > 64 (online-softmax batches, direct gather)
    if (c > 64) {
        float m_run = bm;
        for (int b0 = 64; b0 < c; b0 += 32) {
            int j = b0 + lane;
            float s = -INFINITY;
            if (j < c) {
                const unsigned short* kp = kh + hb + ((size_t)sIdx[g][j] << 5);
                float d = 0.0f;
                #pragma unroll
                for (int i = 0; i < 4; ++i) {
                    short8 k8 = *(const short8*)(kp + i * 8);
                    #pragma unroll
                    for (int e = 0; e < 8; ++e)
                        d = fmaf(qreg[i * 8 + e], b2f((unsigned short)k8[e]), d);
                }
                s = d * sc;
            }
            float bm2 = s;
            #pragma unroll
            for (int o2 = 16; o2; o2 >>= 1) bm2 = fmaxf(bm2, __shfl_xor(bm2, o2, 32));
            float newM = fmaxf(m_run, bm2);
            float p = (j < c) ? __expf(s - newM) : 0.0f;
            float bs = p;
            #pragma unroll
            for (int o2 = 16; o2; o2 >>= 1) bs += __shfl_xor(bs, o2, 32);
            float scale = __expf(m_run - newM);
            S = S * scale + bs;
            acc *= scale;
            int lim = min(32, c - b0);
            const unsigned short* vbase = vh + hb + lane;
            for (int jj = 0; jj < lim; ++jj) {
                float pj = __shfl(p, jj, 32);
                acc = fmaf(pj, b2f(vbase[(size_t)sIdx[g][b0 + jj] << 5]), acc);
            }
            m_run = newM;
        }
    }
    y[(size_t)n * 256 + h * 32 + lane] = f2b(acc / S);
}

extern "C" void kernel_launch(void* const* d_in, const int* in_sizes, int n_in,
                              void* d_out, int out_size, void* d_ws, size_t ws_size,
                              hipStream_t stream) {
    const float* x   = (const float*)d_in[0];
    const int*   ei  = (const int*)d_in[1];
    const float* Wq  = (const float*)d_in[2];  const float* bq  = (const float*)d_in[3];
    const float* Wk  = (const float*)d_in[4];  const float* bk  = (const float*)d_in[5];
    const float* Wv  = (const float*)d_in[6];  const float* bv  = (const float*)d_in[7];
    const float* Wo  = (const float*)d_in[8];  const float* bo  = (const float*)d_in[9];
    const float* g1  = (const float*)d_in[10]; const float* b1  = (const float*)d_in[11];
    const float* g2  = (const float*)d_in[12]; const float* b2  = (const float*)d_in[13];
    const float* Wm1 = (const float*)d_in[14]; const float* bm1 = (const float*)d_in[15];
    const float* Wm2 = (const float*)d_in[16]; const float* bm2 = (const float*)d_in[17];
    float* out = (float*)d_out;
    int E = in_sizes[1] / 2;   // 135168
    int nadj = (E + 511) / 512;

    char* WS = (char*)d_ws;
    const size_t MB = 1u << 20;
    unsigned*       bitmap = (unsigned*)WS;                        // [0,2MB)
    int*            flag   = (int*)(WS + 2 * MB);                  // 4B
    float*          psum   = (float*)(WS + 2 * MB + 4096);         // 64KB [N][4]
    float*          psum2  = (float*)(WS + 2 * MB + 4096 + 65536); // 64KB
    unsigned short* wbf    = (unsigned short*)(WS + 3 * MB);       // 1MB
    unsigned short* y      = (unsigned short*)(WS + 4 * MB);       // 2MB
    float*          x1     = (float*)(WS + 6 * MB);                // 4MB
    unsigned short* m1     = (unsigned short*)(WS + 10 * MB);      // 4MB
    unsigned short* h      = (unsigned short*)(WS + 14 * MB);      // 2MB
    unsigned short* qh     = (unsigned short*)(WS + 16 * MB);      // 2MB [8][N][32]
    unsigned short* kh     = (unsigned short*)(WS + 18 * MB);      // 2MB
    unsigned short* vh     = (unsigned short*)(WS + 20 * MB);      // 2MB

    const unsigned short* WTqkv = wbf;            // q|k|v stacked along M
    const unsigned short* WTo   = wbf + 196608;
    const unsigned short* WTm1  = wbf + 262144;
    const unsigned short* WTm2  = wbf + 393216;

    // 1) convw + zero bitmap + detect + LN1
    prep_kernel<<<6657, 256, 0, stream>>>(Wq, Wk, Wv, Wo, Wm1, Wm2, wbf,
                                          (uint4*)bitmap, ei, flag, x, g1, b1, h);
    // 2) build_adj (blocks [0,nadj)) + qkv GEMM, head-major stores
    gemm_bf16<256, 3, false, false><<<nadj + 768, 512, 0, stream>>>(h, nullptr,
            nullptr, nullptr, nullptr, nullptr, WTqkv, bq, bk, bv, nullptr,
            nullptr, qh, kh, vh, nullptr, nullptr, 768, ei, E, flag, bitmap, nadj);
    // 3) attention (XCD-pinned heads, single-pass softmax)
    attn_kernel<<<N_NODES, 256, 0, stream>>>(qh, kh, vh, bitmap, y);
    // 4) x1 = x + y @ Wo + bo   (+ per-row partial LN2 stats)
    gemm_bf16<256, 2, false, true><<<dim3(64, 4), 512, 0, stream>>>(y, nullptr,
            nullptr, nullptr, nullptr, nullptr, WTo, bo, nullptr, nullptr, x,
            x1, nullptr, nullptr, nullptr, psum, psum2, 256, nullptr, 0, nullptr, nullptr, 0);
    // 5) m1 = gelu(LN2(x1) @ Wm1 + bm1)   (LN2 applied during A-staging)
    gemm_bf16<256, 1, true, false><<<dim3(64, 8), 512, 0, stream>>>(nullptr, x1,
            psum, psum2, g2, b2, WTm1, bm1, nullptr, nullptr, nullptr,
            nullptr, m1, nullptr, nullptr, nullptr, nullptr, 512, nullptr, 0, nullptr, nullptr, 0);
    // 6) out = x1 + m1 @ Wm2 + bm2
    gemm_bf16<512, 2, false, false><<<dim3(64, 4), 512, 0, stream>>>(m1, nullptr,
            nullptr, nullptr, nullptr, nullptr, WTm2, bm2, nullptr, nullptr, x1,
            out, nullptr, nullptr, nullptr, nullptr, nullptr, 256, nullptr, 0, nullptr, nullptr, 0);
}

// Round 15
// 70.303 us; speedup vs baseline: 4.4299x; 1.0680x over previous
//
#include <hip/hip_runtime.h>
#include <hip/hip_bf16.h>

#define N_NODES 4096
#define D_MODEL 256
#define NWORDS 128   // bitmap words per row (4096/32)
#define CAP 96       // max neighbors per row (avg ~33; 96 is +11 sigma)

typedef __attribute__((ext_vector_type(8))) short short8;
typedef __attribute__((ext_vector_type(4))) short short4v;
typedef __attribute__((ext_vector_type(4))) float f32x4;

__device__ __forceinline__ unsigned short f2b(float f) {  // fp32 -> bf16 RTN
    unsigned u = __float_as_uint(f);
    return (unsigned short)((u + 0x7FFFu + ((u >> 16) & 1u)) >> 16);
}
__device__ __forceinline__ float b2f(unsigned short u) {
    return __uint_as_float((unsigned)u << 16);
}

// ---- prep: convw (0..2047) | zero bitmap (2048..2559) | detect (2560)
// ----       | LN1 rows (2561..6656) ---------------------------------------
__global__ __launch_bounds__(256) void prep_kernel(const float* __restrict__ Wq,
        const float* __restrict__ Wk, const float* __restrict__ Wv,
        const float* __restrict__ Wo, const float* __restrict__ Wm1,
        const float* __restrict__ Wm2, unsigned short* __restrict__ wbf,
        uint4* __restrict__ bitmap, const int* __restrict__ ei,
        int* __restrict__ flag, const float* __restrict__ x,
        const float* __restrict__ g1, const float* __restrict__ b1,
        unsigned short* __restrict__ h) {
    int b = blockIdx.x, t = threadIdx.x;
    if (b < 2048) {                       // weight fp32 [K][M] -> bf16 [M][K]
        int e = b * 256 + t;              // 0..524287
        const float* W; int base, K, M;
        if (e < 262144) {
            int r = e >> 16;
            W = (r == 0) ? Wq : (r == 1) ? Wk : (r == 2) ? Wv : Wo;
            base = r << 16; K = 256; M = 256;
        } else if (e < 393216) { W = Wm1; base = 262144; K = 256; M = 512; }
        else                   { W = Wm2; base = 393216; K = 512; M = 256; }
        int i = e - base;
        int m = i / K, k = i - m * K;
        wbf[e] = f2b(W[k * M + m]);
    } else if (b < 2560) {                // zero the 2MB bitmap
        bitmap[(size_t)(b - 2048) * 256 + t] = uint4{0, 0, 0, 0};
    } else if (b == 2560) {               // edge dtype detect
        if (t == 0) {
            int is64 = 1;
            for (int i = 1; i < 128; i += 2)
                if (ei[i] != 0) { is64 = 0; break; }
            *flag = is64;
        }
    } else {                              // LayerNorm1: one row per block
        int row = b - 2561;
        float v = x[row * D_MODEL + t];
        __shared__ float red[4];
        float s = v;
        #pragma unroll
        for (int off = 32; off; off >>= 1) s += __shfl_down(s, off, 64);
        if ((t & 63) == 0) red[t >> 6] = s;
        __syncthreads();
        float mu = (red[0] + red[1] + red[2] + red[3]) * (1.0f / 256.0f);
        __syncthreads();
        float d = v - mu;
        float s2 = d * d;
        #pragma unroll
        for (int off = 32; off; off >>= 1) s2 += __shfl_down(s2, off, 64);
        if ((t & 63) == 0) red[t >> 6] = s2;
        __syncthreads();
        float var = (red[0] + red[1] + red[2] + red[3]) * (1.0f / 256.0f);
        h[row * D_MODEL + t] = f2b(d * rsqrtf(var + 1e-5f) * g1[t] + b1[t]);
    }
}

// ---- bf16 MFMA GEMM: 64x64 tile, 512 thr / 8 waves, BK=64 ----------------
// MODE 1: +bias,GELU -> bf16 | 2: +bias+R -> f32 | 3: qkv 3-part bias,
//   head-major stores q/k/v[h][N][32] (+ build_adj in blocks [0,nadj))
// LNA:   A is f32 + per-row partial stats -> layernorm during A-staging
// STATS: epilogue emits per-row partial sum/sumsq of C (for downstream LN)
template <int K, int MODE, bool LNA, bool STATS>
__global__ __launch_bounds__(512) void gemm_bf16(const unsigned short* __restrict__ A,
        const float* __restrict__ Af, const float* __restrict__ psum,
        const float* __restrict__ psum2, const float* __restrict__ lng,
        const float* __restrict__ lnb, const unsigned short* __restrict__ BT,
        const float* __restrict__ bias, const float* __restrict__ bias_k,
        const float* __restrict__ bias_v, const float* __restrict__ R,
        float* __restrict__ Cf, unsigned short* __restrict__ Cb,
        unsigned short* __restrict__ Ck, unsigned short* __restrict__ Cv,
        float* __restrict__ opsum, float* __restrict__ opsum2, int M,
        const int* __restrict__ ei, int E, const int* __restrict__ flag,
        unsigned* __restrict__ bitmap, int nadj) {
    int tid = threadIdx.x;
    if (MODE == 3 && (int)blockIdx.x < nadj) {   // fused edge scatter
        int e = (int)blockIdx.x * 512 + tid;
        if (e < E) {
            int n, m;
            if (*flag) { n = ei[2 * e]; m = ei[2 * (E + e)]; }
            else       { n = ei[e];     m = ei[E + e]; }
            atomicOr(&bitmap[n * NWORDS + (m >> 5)], 1u << (m & 31));
        }
        return;
    }
    __shared__ unsigned short Asm[64][72];
    __shared__ unsigned short Bsm[64][72];
    __shared__ float psA[64][2], psA2[64][2];
    __shared__ float muS[64], invS[64];

    int bx2  = (MODE == 3) ? ((int)blockIdx.x - nadj) : 0;
    int brow = (MODE == 3) ? ((bx2 & 63) << 6) : ((int)blockIdx.x << 6);
    int by   = (MODE == 3) ? (bx2 >> 6) : (int)blockIdx.y;
    int bcol = by << 6;
    int wid = tid >> 6, lane = tid & 63;
    int wr = wid >> 1, wc = wid & 1;             // 4 row-waves x 2 col-waves
    int l15 = lane & 15, lhi = lane >> 4;
    int r0 = tid >> 3, c0 = (tid & 7) << 3;

    float mu_r = 0.f, inv_r = 0.f;
    if (LNA) {   // combine partial stats once per block
        if (tid < 64) {
            float4 s4 = ((const float4*)psum)[brow + tid];
            float4 q4 = ((const float4*)psum2)[brow + tid];
            float S  = s4.x + s4.y + s4.z + s4.w;
            float S2 = q4.x + q4.y + q4.z + q4.w;
            float mu = S * (1.0f / 256.0f);
            muS[tid] = mu;
            invS[tid] = rsqrtf(S2 * (1.0f / 256.0f) - mu * mu + 1e-5f);
        }
        __syncthreads();
        mu_r = muS[r0]; inv_r = invS[r0];
    }

    const unsigned short* Bp = BT + (size_t)(bcol + r0) * K + c0;
    f32x4 acc[2] = {};
    short8 areg;
    float4 xa, xb, ga, gb, ba, bb;
    if (LNA) {
        const float* Xp = Af + (size_t)(brow + r0) * 256 + c0;
        xa = *(const float4*)(Xp);
        xb = *(const float4*)(Xp + 4);
        ga = *(const float4*)(lng + c0); gb = *(const float4*)(lng + c0 + 4);
        ba = *(const float4*)(lnb + c0); bb = *(const float4*)(lnb + c0 + 4);
    } else {
        areg = *(const short8*)(A + (size_t)(brow + r0) * K + c0);
    }
    short8 breg = *(const short8*)(Bp);

    #pragma unroll
    for (int k0 = 0; k0 < K; k0 += 64) {
        if (LNA) {   // layernorm on the fly into LDS
            float xv[8] = {xa.x, xa.y, xa.z, xa.w, xb.x, xb.y, xb.z, xb.w};
            float gv[8] = {ga.x, ga.y, ga.z, ga.w, gb.x, gb.y, gb.z, gb.w};
            float bv[8] = {ba.x, ba.y, ba.z, ba.w, bb.x, bb.y, bb.z, bb.w};
            short8 o;
            #pragma unroll
            for (int j = 0; j < 8; ++j)
                o[j] = (short)f2b((xv[j] - mu_r) * inv_r * gv[j] + bv[j]);
            *(short8*)&Asm[r0][c0] = o;
        } else {
            *(short8*)&Asm[r0][c0] = areg;
        }
        *(short8*)&Bsm[r0][c0] = breg;
        __syncthreads();
        if (k0 + 64 < K) {                      // prefetch next K-step
            if (LNA) {
                const float* Xp = Af + (size_t)(brow + r0) * 256 + k0 + 64 + c0;
                xa = *(const float4*)(Xp);
                xb = *(const float4*)(Xp + 4);
                ga = *(const float4*)(lng + k0 + 64 + c0);
                gb = *(const float4*)(lng + k0 + 64 + c0 + 4);
                ba = *(const float4*)(lnb + k0 + 64 + c0);
                bb = *(const float4*)(lnb + k0 + 64 + c0 + 4);
            } else {
                areg = *(const short8*)(A + (size_t)(brow + r0) * K + k0 + 64 + c0);
            }
            breg = *(const short8*)(Bp + k0 + 64);
        }
        #pragma unroll
        for (int ks = 0; ks < 2; ++ks) {
            int kc = ks * 32 + lhi * 8;
            short8 a_0 = *(const short8*)&Asm[wr * 16 + l15][kc];
            short8 b_0 = *(const short8*)&Bsm[wc * 32 + l15][kc];
            short8 b_1 = *(const short8*)&Bsm[wc * 32 + 16 + l15][kc];
            acc[0] = __builtin_amdgcn_mfma_f32_16x16x32_bf16(a_0, b_0, acc[0], 0, 0, 0);
            acc[1] = __builtin_amdgcn_mfma_f32_16x16x32_bf16(a_0, b_1, acc[1], 0, 0, 0);
        }
        __syncthreads();
    }

    float cs[2][4];
    #pragma unroll
    for (int sn = 0; sn < 2; ++sn) {
        int col = bcol + wc * 32 + sn * 16 + l15;
        float bs;
        if (MODE == 3)
            bs = (col < 256) ? bias[col]
               : (col < 512) ? bias_k[col - 256] : bias_v[col - 512];
        else
            bs = bias[col];
        #pragma unroll
        for (int r = 0; r < 4; ++r) {
            int row = brow + wr * 16 + lhi * 4 + r;
            float c = acc[sn][r] + bs;
            if (MODE == 1) {
                c = 0.5f * c * (1.0f + erff(c * 0.70710678118654752f));
                Cb[(size_t)row * M + col] = f2b(c);
            } else if (MODE == 2) {
                c += R[(size_t)row * M + col];
                Cf[(size_t)row * M + col] = c;
            } else if (MODE == 3) {
                // head-major: part (q/k/v), head = cc>>5, dim = cc&31
                int part = col >> 8, cc = col & 255;
                unsigned short* dst = (part == 0) ? Cb : (part == 1) ? Ck : Cv;
                dst[(((size_t)(cc >> 5) * N_NODES + row) << 5) + (cc & 31)] = f2b(c);
            } else {
                Cb[(size_t)row * M + col] = f2b(c);
            }
            if (STATS) cs[sn][r] = c;
        }
    }
    if (STATS) {   // deterministic per-row partial stats over this 64-col strip
        #pragma unroll
        for (int r = 0; r < 4; ++r) {
            float s  = cs[0][r] + cs[1][r];
            float s2 = cs[0][r] * cs[0][r] + cs[1][r] * cs[1][r];
            #pragma unroll
            for (int off = 1; off < 16; off <<= 1) {
                s  += __shfl_xor(s, off, 64);
                s2 += __shfl_xor(s2, off, 64);
            }
            if (l15 == 0) {
                int rl = wr * 16 + lhi * 4 + r;
                psA[rl][wc] = s; psA2[rl][wc] = s2;
            }
        }
        __syncthreads();
        if (tid < 64) {
            opsum [(size_t)(brow + tid) * 4 + by] = psA[tid][0] + psA[tid][1];
            opsum2[(size_t)(brow + tid) * 4 + by] = psA2[tid][0] + psA2[tid][1];
        }
    }
}

// ---------------- sparse attention: XCD-pinned heads, single-pass softmax,
// ---------------- PV via ds_read_b64_tr_b16 hardware transpose ------------
// block = 8 rows x 1 head; head = blockIdx.x & 7 (per-XCD L2 pinning).
// V staged to LDS in 4x16 subtiles (jblock stride 136 elems, 16B pad);
// PV: 16 tr-reads (4 neighbors each) + float4 p broadcasts — replaces
// 64 ds_read_u16 + 64 shfl (the DS-pipe bottleneck).
#define TRLOAD(dst_, OFF_) \
    asm volatile("ds_read_b64_tr_b16 %0, %1 offset:" #OFF_ \
                 : "=v"(dst_) : "v"(trbase))
#define PVSTEP(tv_, b_) { \
    float4 pv = *(const float4*)&pArr[g][4 * (b_)]; \
    acc = fmaf(pv.x, b2f((unsigned short)tv_[0]), acc); \
    acc = fmaf(pv.y, b2f((unsigned short)tv_[1]), acc); \
    acc = fmaf(pv.z, b2f((unsigned short)tv_[2]), acc); \
    acc = fmaf(pv.w, b2f((unsigned short)tv_[3]), acc); }

__global__ __launch_bounds__(256) void attn_kernel(const unsigned short* __restrict__ qh,
        const unsigned short* __restrict__ kh, const unsigned short* __restrict__ vh,
        const unsigned* __restrict__ bitmap, unsigned short* __restrict__ y) {
    int bid = blockIdx.x, tid = threadIdx.x;
    int h = bid & 7, oct = bid >> 3;
    int g = tid >> 5, lane = tid & 31;
    int n = oct * 8 + g;
    __shared__ int sIdx[8][CAP];
    __shared__ unsigned short Vst[8][2176];   // 16 jblocks x 136 elems (4x16 subtiles + pad)
    __shared__ float pArr[8][64];

    // q load first: latency hides under the bitmap scan
    const unsigned short* qp = qh + (((size_t)h * N_NODES + n) << 5);
    float qreg[32];
    #pragma unroll
    for (int i = 0; i < 4; ++i) {
        short8 q8 = *(const short8*)(qp + i * 8);
        #pragma unroll
        for (int j = 0; j < 8; ++j) qreg[i * 8 + j] = b2f((unsigned short)q8[j]);
    }

    // group-local bitmap scan: lane holds 4 words (uint4 = its 16B slice)
    uint4 w4 = ((const uint4*)(bitmap + (size_t)n * NWORDS))[lane];
    unsigned words[4] = {w4.x, w4.y, w4.z, w4.w};
    int pc = __popc(w4.x) + __popc(w4.y) + __popc(w4.z) + __popc(w4.w);
    int pre = pc;
    #pragma unroll
    for (int off = 1; off < 32; off <<= 1) {
        int u = __shfl_up(pre, off, 32);
        if (lane >= off) pre += u;
    }
    int c = __shfl(pre, 31, 32);          // row neighbor count
    int off = pre - pc;                   // exclusive prefix
    #pragma unroll
    for (int i = 0; i < 4; ++i) {
        unsigned word = words[i];
        int wbase = ((lane << 2) + i) << 5;
        while (word) {
            int bit = __ffs(word) - 1;
            word &= word - 1;
            if (off < CAP) sIdx[g][off] = wbase + bit;
            ++off;
        }
    }
    c = min(c, CAP);
    for (int i = c + lane; i < 64; i += 32) sIdx[g][i] = 0;   // pad: safe index
    __syncthreads();

    int idx_a = sIdx[g][lane], idx_b = sIdx[g][lane + 32];
    const size_t hb = (size_t)h * N_NODES << 5;

    // issue V staging loads FIRST (latency hides under K gather + dot)
    const unsigned short* va = vh + hb + ((size_t)idx_a << 5);
    const unsigned short* vb = vh + hb + ((size_t)idx_b << 5);
    short8 va0 = *(const short8*)(va);      short8 va1 = *(const short8*)(va + 8);
    short8 va2 = *(const short8*)(va + 16); short8 va3 = *(const short8*)(va + 24);
    short8 vb0 = *(const short8*)(vb);      short8 vb1 = *(const short8*)(vb + 8);
    short8 vb2 = *(const short8*)(vb + 16); short8 vb3 = *(const short8*)(vb + 24);

    // K gather (issued after V; dot's wait drains V too)
    const unsigned short* ka = kh + hb + ((size_t)idx_a << 5);
    const unsigned short* kb = kh + hb + ((size_t)idx_b << 5);
    short8 ka0 = *(const short8*)(ka);      short8 ka1 = *(const short8*)(ka + 8);
    short8 ka2 = *(const short8*)(ka + 16); short8 ka3 = *(const short8*)(ka + 24);
    short8 kb0 = *(const short8*)(kb);      short8 kb1 = *(const short8*)(kb + 8);
    short8 kb2 = *(const short8*)(kb + 16); short8 kb3 = *(const short8*)(kb + 24);

    // stage V to LDS in tr-subtile layout:
    // elem(j,d) = (j>>2)*136 + (d>>4)*64 + (j&3)*16 + (d&15)
    {
        unsigned short* vr = &Vst[g][(lane >> 2) * 136 + (lane & 3) * 16];
        *(short8*)(vr + 0)  = va0;           // dims 0-7
        *(short8*)(vr + 8)  = va1;           // dims 8-15
        *(short8*)(vr + 64) = va2;           // dims 16-23
        *(short8*)(vr + 72) = va3;           // dims 24-31
        unsigned short* vr2 = vr + 8 * 136;  // row lane+32
        *(short8*)(vr2 + 0)  = vb0;
        *(short8*)(vr2 + 8)  = vb1;
        *(short8*)(vr2 + 64) = vb2;
        *(short8*)(vr2 + 72) = vb3;
    }

    // dual dot with split chains for ILP
    float da0 = 0.f, da1 = 0.f, db0 = 0.f, db1 = 0.f;
    #pragma unroll
    for (int e = 0; e < 8; ++e) {
        da0 = fmaf(qreg[e],      b2f((unsigned short)ka0[e]), da0);
        da1 = fmaf(qreg[8 + e],  b2f((unsigned short)ka1[e]), da1);
        da0 = fmaf(qreg[16 + e], b2f((unsigned short)ka2[e]), da0);
        da1 = fmaf(qreg[24 + e], b2f((unsigned short)ka3[e]), da1);
        db0 = fmaf(qreg[e],      b2f((unsigned short)kb0[e]), db0);
        db1 = fmaf(qreg[8 + e],  b2f((unsigned short)kb1[e]), db1);
        db0 = fmaf(qreg[16 + e], b2f((unsigned short)kb2[e]), db0);
        db1 = fmaf(qreg[24 + e], b2f((unsigned short)kb3[e]), db1);
    }
    const float sc = 0.17677669529663687f;   // 1/sqrt(32)
    float s_a = (lane < c)      ? (da0 + da1) * sc : -INFINITY;
    float s_b = (lane + 32 < c) ? (db0 + db1) * sc : -INFINITY;

    // single-pass softmax over (up to) 64 neighbors
    float bm = fmaxf(s_a, s_b);
    #pragma unroll
    for (int o2 = 16; o2; o2 >>= 1) bm = fmaxf(bm, __shfl_xor(bm, o2, 32));
    float p_a = (lane < c)      ? __expf(s_a - bm) : 0.0f;
    float p_b = (lane + 32 < c) ? __expf(s_b - bm) : 0.0f;
    float S = p_a + p_b;
    #pragma unroll
    for (int o2 = 16; o2; o2 >>= 1) S += __shfl_xor(S, o2, 32);
    pArr[g][lane] = p_a;
    pArr[g][lane + 32] = p_b;

    // PV: 16 hardware-transpose reads; lane = output dim.
    // lane vaddr = group base + dblk*128B + (l&15)*8B; offset walks jblocks.
    unsigned trbase = (unsigned)(uintptr_t)(&Vst[g][0])
                    + ((unsigned)(lane >> 4) << 7) + ((unsigned)(lane & 15) << 3);
    asm volatile("s_waitcnt lgkmcnt(0)" ::: "memory");   // Vst + pArr written
    short4v t0, t1, t2, t3, t4, t5, t6, t7, t8, t9, t10, t11, t12, t13, t14, t15;
    TRLOAD(t0, 0);     TRLOAD(t1, 272);  TRLOAD(t2, 544);  TRLOAD(t3, 816);
    TRLOAD(t4, 1088);  TRLOAD(t5, 1360); TRLOAD(t6, 1632); TRLOAD(t7, 1904);
    TRLOAD(t8, 2176);  TRLOAD(t9, 2448); TRLOAD(t10, 2720); TRLOAD(t11, 2992);
    TRLOAD(t12, 3264); TRLOAD(t13, 3536); TRLOAD(t14, 3808); TRLOAD(t15, 4080);
    asm volatile("s_waitcnt lgkmcnt(0)" ::: "memory");
    __builtin_amdgcn_sched_barrier(0);

    float acc = 0.0f;
    PVSTEP(t0, 0)   PVSTEP(t1, 1)   PVSTEP(t2, 2)   PVSTEP(t3, 3)
    PVSTEP(t4, 4)   PVSTEP(t5, 5)   PVSTEP(t6, 6)   PVSTEP(t7, 7)
    PVSTEP(t8, 8)   PVSTEP(t9, 9)   PVSTEP(t10, 10) PVSTEP(t11, 11)
    PVSTEP(t12, 12) PVSTEP(t13, 13) PVSTEP(t14, 14) PVSTEP(t15, 15)

    // rare fallback: rows with c > 64 (online-softmax batches, direct gather)
    if (c > 64) {
        float m_run = bm;
        for (int b0 = 64; b0 < c; b0 += 32) {
            int j = b0 + lane;
            float s = -INFINITY;
            if (j < c) {
                const unsigned short* kp = kh + hb + ((size_t)sIdx[g][j] << 5);
                float d = 0.0f;
                #pragma unroll
                for (int i = 0; i < 4; ++i) {
                    short8 k8 = *(const short8*)(kp + i * 8);
                    #pragma unroll
                    for (int e = 0; e < 8; ++e)
                        d = fmaf(qreg[i * 8 + e], b2f((unsigned short)k8[e]), d);
                }
                s = d * sc;
            }
            float bm2 = s;
            #pragma unroll
            for (int o2 = 16; o2; o2 >>= 1) bm2 = fmaxf(bm2, __shfl_xor(bm2, o2, 32));
            float newM = fmaxf(m_run, bm2);
            float p = (j < c) ? __expf(s - newM) : 0.0f;
            float bs = p;
            #pragma unroll
            for (int o2 = 16; o2; o2 >>= 1) bs += __shfl_xor(bs, o2, 32);
            float scale = __expf(m_run - newM);
            S = S * scale + bs;
            acc *= scale;
            int lim = min(32, c - b0);
            const unsigned short* vbase = vh + hb + lane;
            for (int jj = 0; jj < lim; ++jj) {
                float pj = __shfl(p, jj, 32);
                acc = fmaf(pj, b2f(vbase[(size_t)sIdx[g][b0 + jj] << 5]), acc);
            }
            m_run = newM;
        }
    }
    y[(size_t)n * 256 + h * 32 + lane] = f2b(acc / S);
}

extern "C" void kernel_launch(void* const* d_in, const int* in_sizes, int n_in,
                              void* d_out, int out_size, void* d_ws, size_t ws_size,
                              hipStream_t stream) {
    const float* x   = (const float*)d_in[0];
    const int*   ei  = (const int*)d_in[1];
    const float* Wq  = (const float*)d_in[2];  const float* bq  = (const float*)d_in[3];
    const float* Wk  = (const float*)d_in[4];  const float* bk  = (const float*)d_in[5];
    const float* Wv  = (const float*)d_in[6];  const float* bv  = (const float*)d_in[7];
    const float* Wo  = (const float*)d_in[8];  const float* bo  = (const float*)d_in[9];
    const float* g1  = (const float*)d_in[10]; const float* b1  = (const float*)d_in[11];
    const float* g2  = (const float*)d_in[12]; const float* b2  = (const float*)d_in[13];
    const float* Wm1 = (const float*)d_in[14]; const float* bm1 = (const float*)d_in[15];
    const float* Wm2 = (const float*)d_in[16]; const float* bm2 = (const float*)d_in[17];
    float* out = (float*)d_out;
    int E = in_sizes[1] / 2;   // 135168
    int nadj = (E + 511) / 512;

    char* WS = (char*)d_ws;
    const size_t MB = 1u << 20;
    unsigned*       bitmap = (unsigned*)WS;                        // [0,2MB)
    int*            flag   = (int*)(WS + 2 * MB);                  // 4B
    float*          psum   = (float*)(WS + 2 * MB + 4096);         // 64KB [N][4]
    float*          psum2  = (float*)(WS + 2 * MB + 4096 + 65536); // 64KB
    unsigned short* wbf    = (unsigned short*)(WS + 3 * MB);       // 1MB
    unsigned short* y      = (unsigned short*)(WS + 4 * MB);       // 2MB
    float*          x1     = (float*)(WS + 6 * MB);                // 4MB
    unsigned short* m1     = (unsigned short*)(WS + 10 * MB);      // 4MB
    unsigned short* h      = (unsigned short*)(WS + 14 * MB);      // 2MB
    unsigned short* qh     = (unsigned short*)(WS + 16 * MB);      // 2MB [8][N][32]
    unsigned short* kh     = (unsigned short*)(WS + 18 * MB);      // 2MB
    unsigned short* vh     = (unsigned short*)(WS + 20 * MB);      // 2MB

    const unsigned short* WTqkv = wbf;            // q|k|v stacked along M
    const unsigned short* WTo   = wbf + 196608;
    const unsigned short* WTm1  = wbf + 262144;
    const unsigned short* WTm2  = wbf + 393216;

    // 1) convw + zero bitmap + detect + LN1
    prep_kernel<<<6657, 256, 0, stream>>>(Wq, Wk, Wv, Wo, Wm1, Wm2, wbf,
                                          (uint4*)bitmap, ei, flag, x, g1, b1, h);
    // 2) build_adj (blocks [0,nadj)) + qkv GEMM, head-major stores
    gemm_bf16<256, 3, false, false><<<nadj + 768, 512, 0, stream>>>(h, nullptr,
            nullptr, nullptr, nullptr, nullptr, WTqkv, bq, bk, bv, nullptr,
            nullptr, qh, kh, vh, nullptr, nullptr, 768, ei, E, flag, bitmap, nadj);
    // 3) attention (XCD-pinned heads, single-pass softmax, tr-read PV)
    attn_kernel<<<N_NODES, 256, 0, stream>>>(qh, kh, vh, bitmap, y);
    // 4) x1 = x + y @ Wo + bo   (+ per-row partial LN2 stats)
    gemm_bf16<256, 2, false, true><<<dim3(64, 4), 512, 0, stream>>>(y, nullptr,
            nullptr, nullptr, nullptr, nullptr, WTo, bo, nullptr, nullptr, x,
            x1, nullptr, nullptr, nullptr, psum, psum2, 256, nullptr, 0, nullptr, nullptr, 0);
    // 5) m1 = gelu(LN2(x1) @ Wm1 + bm1)   (LN2 applied during A-staging)
    gemm_bf16<256, 1, true, false><<<dim3(64, 8), 512, 0, stream>>>(nullptr, x1,
            psum, psum2, g2, b2, WTm1, bm1, nullptr, nullptr, nullptr,
            nullptr, m1, nullptr, nullptr, nullptr, nullptr, 512, nullptr, 0, nullptr, nullptr, 0);
    // 6) out = x1 + m1 @ Wm2 + bm2
    gemm_bf16<512, 2, false, false><<<dim3(64, 4), 512, 0, stream>>>(m1, nullptr,
            nullptr, nullptr, nullptr, nullptr, WTm2, bm2, nullptr, nullptr, x1,
            out, nullptr, nullptr, nullptr, nullptr, nullptr, 256, nullptr, 0, nullptr, nullptr, 0);
}